// Round 12
// baseline (1699.631 us; speedup 1.0000x reference)
//
#include <hip/hip_runtime.h>
#include <math.h>

typedef __attribute__((ext_vector_type(8))) short bf16x8;
typedef __attribute__((ext_vector_type(4))) float f32x4;
typedef __attribute__((ext_vector_type(4))) unsigned short us4;

__device__ inline unsigned short f2bf(float f){
  unsigned u = __float_as_uint(f);
  u += 0x7fff + ((u>>16)&1);
  return (unsigned short)(u>>16);
}

// offset arg ALWAYS 0 (round-4 failure: imm-offset semantics ambiguous).
__device__ __forceinline__ void gload16(const unsigned short* g, char* l){
  __builtin_amdgcn_global_load_lds(
      (const __attribute__((address_space(1))) unsigned int*)g,
      (__attribute__((address_space(3))) unsigned int*)l, 16, 0, 0);
}

// ---------- feat NCHW fp32 -> featT NHWC bf16 (padded width Wp=W+2) ----------
__global__ __launch_bounds__(256) void k_trans(const float* __restrict__ feat,
    unsigned short* __restrict__ ft, int H, int W, int Wp, int y_begin,
    int slot_base, int RBf)
{
  int t = threadIdx.x;
  int lane = t & 63, wv = t >> 6;
  int x = blockIdx.x*64 + lane;
  int y = y_begin + blockIdx.y;
  int b = blockIdx.z;
  int slot = slot_base + blockIdx.y;
  if (x >= W) return;
  const float* fb = feat + ((size_t)(b*256)*H + y)*W + x;
  unsigned short* dst = ft + (((size_t)b*RBf + slot)*Wp + x + 1)*256;
  #pragma unroll 4
  for (int i=0;i<16;i++){
    int c0 = wv*4 + i*16;
    float v0 = fb[(size_t)(c0+0)*H*W];
    float v1 = fb[(size_t)(c0+1)*H*W];
    float v2 = fb[(size_t)(c0+2)*H*W];
    float v3 = fb[(size_t)(c0+3)*H*W];
    us4 o = { f2bf(v0), f2bf(v1), f2bf(v2), f2bf(v3) };
    *(us4*)(dst + c0) = o;
  }
}

// ---------- zero helpers ----------
__global__ __launch_bounds__(256) void k_zrow(unsigned short* __restrict__ buf,
    long bStr, int Wp, int slot0, int nslots)
{
  long i = ((long)blockIdx.x*256 + threadIdx.x)*8;
  long per_b = (long)nslots*Wp*256;
  if (i >= 4*per_b) return;
  int b = (int)(i / per_b); long r = i % per_b;
  unsigned short* d = buf + (size_t)b*bStr + (size_t)slot0*Wp*256 + r;
  us4 z = {0,0,0,0};
  *(us4*)d = z; *(us4*)(d+4) = z;
}

__global__ __launch_bounds__(256) void k_zcol(unsigned short* __restrict__ buf,
    int Wp, int RB, int W)
{
  long i = ((long)blockIdx.x*256 + threadIdx.x)*8;
  long tot = (long)4*RB*2*256;
  if (i >= tot) return;
  long u = i/8; int q = (int)(u & 31); int side = (int)((u>>5)&1);
  long bs = u>>6; int slot = (int)(bs % RB); int b = (int)(bs / RB);
  unsigned short* d = buf + (((size_t)b*RB + slot)*Wp + (side? W+1 : 0))*256 + q*8;
  us4 z = {0,0,0,0};
  *(us4*)d = z; *(us4*)(d+4) = z;
}

// ---------- weight repacks (layouts verified in round 2) ----------
__global__ __launch_bounds__(256) void k_repack_conv(const float* __restrict__ w,
    const float* __restrict__ g, const float* __restrict__ v,
    unsigned short* __restrict__ wf)
{
  int t = blockIdx.x*256 + threadIdx.x;
  if (t >= 4*256*256) return;
  int ci = t & 255, co = (t>>8) & 255, l = t>>16;
  float s = g[l*256+co] * rsqrtf(v[l*256+co] + 1e-5f);
  const float* wp = w + (size_t)t*9;
  int cb = co>>4, kc = ci>>5;
  int lane = ((ci>>3)&3)*16 + (co&15);
  int e = ci&7;
  size_t base = (((size_t)(l*16+cb)*8 + kc)*9)*512 + (size_t)lane*8 + e;
  #pragma unroll
  for (int tap=0;tap<9;tap++)
    wf[base + (size_t)tap*512] = f2bf(wp[tap]*s);
}

__global__ __launch_bounds__(256) void k_repack_adapt(const float* __restrict__ w,
    unsigned short* __restrict__ wf)
{
  int t = blockIdx.x*256 + threadIdx.x;
  if (t >= 4*256*32) return;
  int o = t & 31, co = (t>>5)&255, l = t>>13;
  int ci0 = o*8;
  const float* wp = w + ((size_t)(l*256+co)*256 + ci0);
  int cb = co>>4, kc = o>>2, lane = (o&3)*16 + (co&15);
  unsigned short* dst = wf + (((size_t)(l*16+cb)*8 + kc)*64 + lane)*8;
  unsigned short tmp[8];
  #pragma unroll
  for (int e=0;e<8;e++) tmp[e] = f2bf(wp[e]);
  *(us4*)dst = *(us4*)tmp; *(us4*)(dst+4) = *(us4*)(tmp+4);
}

__global__ __launch_bounds__(192) void k_repack_pred(const float* __restrict__ w,
    unsigned short* __restrict__ wf)
{
  int t = blockIdx.x*192 + threadIdx.x;
  if (t >= 4*48*32) return;
  int o = t & 31, co = (t>>5)%48, l = t/1536;
  int ci0 = o*8, f = co>>4, kc = o>>2, lane = (o&3)*16 + (co&15);
  unsigned short* dst = wf + ((((size_t)l*8 + kc)*3 + f)*64 + lane)*8;
  #pragma unroll
  for (int e=0;e<8;e++){
    float val = (co<45) ? w[((size_t)(l*45+co)*256 + ci0 + e)] : 0.f;
    dst[e] = f2bf(val);
  }
}

__global__ __launch_bounds__(256) void k_bias(const float* __restrict__ b,
    const float* __restrict__ g, const float* __restrict__ be,
    const float* __restrict__ m, const float* __restrict__ v,
    float* __restrict__ out)
{
  int t = blockIdx.x*256 + threadIdx.x;
  if (t >= 1024) return;
  float s = g[t]*rsqrtf(v[t]+1e-5f);
  out[t] = (b[t]-m[t])*s + be[t];
}

// ---------- MFMA conv: 256co x 2rows x 64px per block, 4 waves ----------
// wave = 64co (cf=4) x 64px x BOTH rows (acc0/acc1, 128 AGPR) -- no A dup.
// QUAD-buffered LDS: one barrier per 2 kc (was 8 barriers -> 4+1), 2 kc of
// staging in flight under 2 computes. PRED: conv2 skips the global write;
// x2 -> swizzled LDS tile -> 45-co pred GEMM + activations + sectioned store.
template<int TAPS, bool RELU, bool PRED>
__global__ __launch_bounds__(256,2) void k_conv6(
    const unsigned short* __restrict__ in, const unsigned short* __restrict__ wf,
    const float* __restrict__ bias, unsigned short* __restrict__ outb,
    int W, int Wp, int y_begin, int y_end, int in_row0, int RBin,
    int out_row0, int RBout,
    const unsigned short* __restrict__ wfP, const float* __restrict__ bp,
    float* __restrict__ outP, int H)
{
  constexpr bool T9    = (TAPS==9);
  constexpr int ROWS   = T9 ? 4 : 2;       // staged input rows
  constexpr int PXS    = T9 ? 72 : 64;     // staged px (reads use <=66)
  constexpr int RSTR   = PXS*64;           // LDS bytes per staged row
  constexpr int BUFB   = ROWS*RSTR;        // 18432 / 8192
  constexpr int NCHK   = BUFB/1024;        // 18 / 8
  constexpr int NFULL  = NCHK/4;
  constexpr int NTAIL  = NCHK - NFULL*4;
  constexpr int CPW    = NFULL + (NTAIL?1:0);
  constexpr int PERROW = PXS*4;            // 16B slots per row
  constexpr int LDSB   = PRED ? (4*BUFB > 65536 ? 4*BUFB : 65536) : 4*BUFB;
  __shared__ __align__(1024) char lds[LDSB];

  int tid = threadIdx.x, lane = tid&63, w = tid>>6;
  int l15 = lane&15, g4 = lane>>4;
  int x0 = blockIdx.x*64;
  int y0 = y_begin + 2*blockIdx.y;
  int b  = blockIdx.z;

  size_t rowEl = (size_t)Wp*256;
  const unsigned short* gb;
  if (T9) gb = in + ((size_t)b*RBin + (y0-1-in_row0))*rowEl + (size_t)x0*256;
  else    gb = in + ((size_t)b*RBin + (y0  -in_row0))*rowEl + (size_t)(x0+1)*256;

  // per-lane staging offsets; inverse-swizzled global source (involution w/ read)
  int Poff[CPW], Coff[CPW];
  #pragma unroll
  for (int i=0;i<CPW;i++){
    int c = (i<NFULL) ? (4*i + w) : (4*NFULL + w);
    int s = c*64 + lane;
    int r = s / PERROW;
    int rem = s - r*PERROW;
    int px = rem>>2, sq = rem&3;
    int slot = sq ^ (px&3) ^ ((px>>2)&3);
    Poff[i] = r*(int)rowEl + px*256 + slot*8;
    Coff[i] = c*1024;
  }

  // per-lane swizzled LDS read offsets (ky applied via +ky*RSTR)
  int vb[T9?12:4];
  if constexpr (T9){
    #pragma unroll
    for (int kx=0;kx<3;kx++)
      #pragma unroll
      for (int pf=0;pf<4;pf++){
        int px = pf*16 + l15 + kx;
        vb[kx*4+pf] = px*64 + ((g4 ^ (px&3) ^ ((px>>2)&3))<<4);
      }
  } else {
    #pragma unroll
    for (int pf=0;pf<4;pf++){
      int px = pf*16 + l15;
      vb[pf] = px*64 + ((g4 ^ (px&3) ^ ((px>>2)&3))<<4);
    }
  }

  // each wave owns 4 consecutive cb blocks (64 co) -- no A duplication
  const unsigned short* wA = wf + (size_t)(w*4)*(8*TAPS*512) + (size_t)lane*8;

  f32x4 acc0[4][4], acc1[4][4];
  #pragma unroll
  for (int i=0;i<4;i++)
    #pragma unroll
    for (int j=0;j<4;j++){
      acc0[i][j] = (f32x4){0.f,0.f,0.f,0.f};
      acc1[i][j] = (f32x4){0.f,0.f,0.f,0.f};
    }

  const unsigned short* gbk = gb;
  auto stage = [&](int jb){
    #pragma unroll
    for (int i=0;i<NFULL;i++) gload16(gbk + Poff[i], (char*)&lds[0] + jb + Coff[i]);
    if constexpr (NTAIL > 0){
      if (w < NTAIL) gload16(gbk + Poff[NFULL], (char*)&lds[0] + jb + Coff[NFULL]);
    }
    gbk += 32;
  };

#define LOADB(KY, KX, BV) { \
  _Pragma("unroll") \
  for (int pf=0;pf<4;pf++) BV[pf] = *(const bf16x8*)(base + (KY)*RSTR + vb[(KX)*4+pf]); }

#define LOADA(G, AV) { \
  _Pragma("unroll") \
  for (int cf=0;cf<4;cf++) AV[cf] = *(const bf16x8*)(wk + (size_t)cf*(8*TAPS*512) + (G)*512); }

#define MM(AC, AV, BV) { \
  _Pragma("unroll") for (int cf=0;cf<4;cf++) \
  _Pragma("unroll") for (int pf=0;pf<4;pf++) \
    AC[cf][pf] = __builtin_amdgcn_mfma_f32_16x16x32_bf16(AV[cf], BV[pf], AC[cf][pf], 0,0,0); }

  auto compute = [&](int kc, const char* base){
    const unsigned short* wk = wA + (size_t)kc*(TAPS*512);
    bf16x8 A[4], B0[4], B1[4];
    __builtin_amdgcn_s_setprio(1);
    if constexpr (T9){
      #pragma unroll
      for (int kx=0;kx<3;kx++){
        LOADB(0,kx,B0) LOADB(1,kx,B1)
        LOADA(0*3+kx,A) MM(acc0,A,B0) MM(acc1,A,B1)
        LOADB(2,kx,B0)
        LOADA(1*3+kx,A) MM(acc0,A,B1) MM(acc1,A,B0)
        LOADB(3,kx,B1)
        LOADA(2*3+kx,A) MM(acc0,A,B0) MM(acc1,A,B1)
      }
    } else {
      LOADB(0,0,B0) LOADB(1,0,B1)
      LOADA(0,A) MM(acc0,A,B0) MM(acc1,A,B1)
    }
    __builtin_amdgcn_s_setprio(0);
  };

  // quad-buffered pipeline: 1 barrier per 2 kc; every buffer overwrite is
  // >=1 barrier after its last reader; every compute reads a buffer drained
  // by the preceding __syncthreads (vmcnt(0) before s_barrier).
  stage(0*BUFB); stage(1*BUFB);
  __syncthreads();
  stage(2*BUFB); compute(0, (const char*)&lds[0] + 0*BUFB);
  stage(3*BUFB); compute(1, (const char*)&lds[0] + 1*BUFB);
  __syncthreads();
  stage(0*BUFB); compute(2, (const char*)&lds[0] + 2*BUFB);
  stage(1*BUFB); compute(3, (const char*)&lds[0] + 3*BUFB);
  __syncthreads();
  stage(2*BUFB); compute(4, (const char*)&lds[0] + 0*BUFB);
  stage(3*BUFB); compute(5, (const char*)&lds[0] + 1*BUFB);
  __syncthreads();
  compute(6, (const char*)&lds[0] + 2*BUFB);
  compute(7, (const char*)&lds[0] + 3*BUFB);
#undef LOADB
#undef LOADA
#undef MM

  if constexpr (!PRED){
    // epilogue: bias (+BN folded) + ReLU, bf16 NHWC store (2 rows per thread)
    bool ok1 = (y0 + 1) < y_end;
    int oslot = y0 - out_row0;
    unsigned short* ob = outb + ((size_t)b*RBout + oslot)*rowEl + 256;
    #pragma unroll
    for (int cf=0; cf<4; ++cf){
      int co0 = w*64 + cf*16 + g4*4;
      f32x4 bb = *(const f32x4*)(bias + co0);
      #pragma unroll
      for (int pf=0; pf<4; ++pf){
        int x = x0 + pf*16 + l15;
        if (x < W){
          float v0 = acc0[cf][pf][0]+bb[0], v1 = acc0[cf][pf][1]+bb[1];
          float v2 = acc0[cf][pf][2]+bb[2], v3 = acc0[cf][pf][3]+bb[3];
          if (RELU){ v0=fmaxf(v0,0.f); v1=fmaxf(v1,0.f); v2=fmaxf(v2,0.f); v3=fmaxf(v3,0.f); }
          us4 o = { f2bf(v0), f2bf(v1), f2bf(v2), f2bf(v3) };
          *(us4*)(ob + (size_t)x*256 + co0) = o;
          if (ok1){
            float u0 = acc1[cf][pf][0]+bb[0], u1 = acc1[cf][pf][1]+bb[1];
            float u2 = acc1[cf][pf][2]+bb[2], u3 = acc1[cf][pf][3]+bb[3];
            if (RELU){ u0=fmaxf(u0,0.f); u1=fmaxf(u1,0.f); u2=fmaxf(u2,0.f); u3=fmaxf(u3,0.f); }
            us4 o1 = { f2bf(u0), f2bf(u1), f2bf(u2), f2bf(u3) };
            *(us4*)(ob + rowEl + (size_t)x*256 + co0) = o1;
          }
        }
      }
    }
  } else {
    // all waves must finish reading staging buffers before xs overwrites lds
    __syncthreads();
    // ---- fused pred: x2 -> swizzled LDS tile [2][64px][32 slots][16B] ----
    unsigned short* xs = (unsigned short*)&lds[0];
    #pragma unroll
    for (int cf=0; cf<4; ++cf){
      int co0 = w*64 + cf*16 + g4*4;
      f32x4 bb = *(const f32x4*)(bias + co0);
      int c16 = co0 >> 3;
      int sub = (g4 & 1) * 8;
      #pragma unroll
      for (int pf=0; pf<4; ++pf){
        int px = pf*16 + l15;
        int slot = c16 ^ (px & 31);
        float v0 = fmaxf(acc0[cf][pf][0]+bb[0],0.f), v1 = fmaxf(acc0[cf][pf][1]+bb[1],0.f);
        float v2 = fmaxf(acc0[cf][pf][2]+bb[2],0.f), v3 = fmaxf(acc0[cf][pf][3]+bb[3],0.f);
        us4 o0 = { f2bf(v0), f2bf(v1), f2bf(v2), f2bf(v3) };
        *(us4*)((char*)xs + ((px*32 + slot)<<4) + sub) = o0;
        float u0 = fmaxf(acc1[cf][pf][0]+bb[0],0.f), u1 = fmaxf(acc1[cf][pf][1]+bb[1],0.f);
        float u2 = fmaxf(acc1[cf][pf][2]+bb[2],0.f), u3 = fmaxf(acc1[cf][pf][3]+bb[3],0.f);
        us4 o1 = { f2bf(u0), f2bf(u1), f2bf(u2), f2bf(u3) };
        *(us4*)((char*)xs + 32768 + ((px*32 + slot)<<4) + sub) = o1;
      }
    }
    __syncthreads();

    // pred GEMM: 48co(3 frags) x (row rw2, px-frag pair pxg) x 256K
    int rw2 = w & 1, pxg = w >> 1;
    f32x4 ap[3][2];
    #pragma unroll
    for (int f=0;f<3;f++){ ap[f][0] = (f32x4){0,0,0,0}; ap[f][1] = (f32x4){0,0,0,0}; }
    #pragma unroll
    for (int kc=0;kc<8;kc++){
      bf16x8 Bf[2];
      #pragma unroll
      for (int t2=0;t2<2;t2++){
        int px = (pxg*2+t2)*16 + l15;
        int slot = (kc*4 + g4) ^ (px & 31);
        Bf[t2] = *(const bf16x8*)((char*)xs + rw2*32768 + ((px*32 + slot)<<4));
      }
      #pragma unroll
      for (int f=0;f<3;f++){
        bf16x8 Af = *(const bf16x8*)(wfP + (((size_t)kc*3 + f)*64 + lane)*8);
        ap[f][0] = __builtin_amdgcn_mfma_f32_16x16x32_bf16(Af, Bf[0], ap[f][0], 0,0,0);
        ap[f][1] = __builtin_amdgcn_mfma_f32_16x16x32_bf16(Af, Bf[1], ap[f][1], 0,0,0);
      }
    }
    int y = y0 + rw2;
    if (y < y_end){
      size_t S = (size_t)H*W;
      #pragma unroll
      for (int f=0;f<3;f++){
        #pragma unroll
        for (int t2=0;t2<2;t2++){
          int px = x0 + (pxg*2+t2)*16 + l15;
          if (px < W){
            #pragma unroll
            for (int r=0;r<4;r++){
              int co = f*16 + g4*4 + r;
              if (co < 45){
                float val = ap[f][t2][r] + bp[co];
                int a_idx = co/15, c = co%15;
                int cum,c0,n;
                if (c<4)       {cum=0;c0=0;n=4;}
                else if (c==4) {cum=4;c0=4;n=1;}
                else if (c<10) {cum=5;c0=5;n=5;}
                else if (c<14) {cum=10;c0=10;n=4;}
                else           {cum=14;c0=14;n=1;}
                if (c==4) val = 1.f/(1.f+expf(-val));
                else if (c==14) val = (val>20.f? val : log1pf(expf(val))) + 1.f;
                size_t chan = ((size_t)(12*cum) + (size_t)((b*3+a_idx)*n + (c-c0)))*S;
                outP[chan + (size_t)y*W + px] = val;
              }
            }
          }
        }
      }
    }
  }
}

// ---------- host ----------
extern "C" void kernel_launch(void* const* d_in, const int* in_sizes, int n_in,
                              void* d_out, int out_size, void* d_ws, size_t ws_size,
                              hipStream_t stream)
{
  static const int Hs[4] = {192,96,48,24};
  static const int Wd[4] = {320,160,80,40};
  const float* feat[4] = {(const float*)d_in[0],(const float*)d_in[1],
                          (const float*)d_in[2],(const float*)d_in[3]};
  const float* adapt_w = (const float*)d_in[4];
  const float* adapt_b = (const float*)d_in[5];
  const float* w1 = (const float*)d_in[6];  const float* b1 = (const float*)d_in[7];
  const float* g1 = (const float*)d_in[8];  const float* be1= (const float*)d_in[9];
  const float* m1 = (const float*)d_in[10]; const float* v1 = (const float*)d_in[11];
  const float* w2 = (const float*)d_in[12]; const float* b2 = (const float*)d_in[13];
  const float* g2 = (const float*)d_in[14]; const float* be2= (const float*)d_in[15];
  const float* m2 = (const float*)d_in[16]; const float* v2 = (const float*)d_in[17];
  const float* wp = (const float*)d_in[18]; const float* bp = (const float*)d_in[19];
  float* out = (float*)d_out;

  char* base = (char*)d_ws;
  size_t off = 0;
  auto alloc = [&](size_t bytes)->char*{
    char* p = base + off; off = (off + bytes + 255) & ~(size_t)255; return p; };

  const size_t WF3_L = (size_t)16*8*9*512;
  const size_t WFA_L = (size_t)16*8*512;
  const size_t WFP_L = (size_t)8*3*512;
  unsigned short* wf1 = (unsigned short*)alloc(4*WF3_L*2);
  unsigned short* wf2 = (unsigned short*)alloc(4*WF3_L*2);
  unsigned short* wfA = (unsigned short*)alloc(4*WFA_L*2);
  unsigned short* wfP = (unsigned short*)alloc(4*WFP_L*2);
  float* biasc1 = (float*)alloc(1024*4);
  float* biasc2 = (float*)alloc(1024*4);
  char*  bufbase = base + off;
  size_t rem = (ws_size > off + 65536) ? (ws_size - off - 65536) : 0;

  k_repack_conv <<<dim3(1024), dim3(256), 0, stream>>>(w1, g1, v1, wf1);
  k_repack_conv <<<dim3(1024), dim3(256), 0, stream>>>(w2, g2, v2, wf2);
  k_repack_adapt<<<dim3(128),  dim3(256), 0, stream>>>(adapt_w, wfA);
  k_repack_pred <<<dim3(32),   dim3(192), 0, stream>>>(wp, wfP);
  k_bias<<<dim3(4), dim3(256), 0, stream>>>(b1, g1, be1, m1, v1, biasc1);
  k_bias<<<dim3(4), dim3(256), 0, stream>>>(b2, g2, be2, m2, v2, biasc2);

  size_t out_off = 0;
  for (int l=0;l<4;l++){
    int H = Hs[l], W = Wd[l], Wp = W + 2;
    size_t S = (size_t)H*W;
    size_t rowEl = (size_t)Wp*256;
    long slotsAvail = (long)(rem / (rowEl*2));
    long Rl = (slotsAvail - 64) / 12;
    int R = (int)(Rl < 2 ? 2 : (Rl > H ? (long)H : Rl));
    int RBf = R + 4, RB1 = R + 2;
    unsigned short* featT = (unsigned short*)bufbase;
    unsigned short* buf0  = featT + ((size_t)4*RBf + 8)*rowEl;
    unsigned short* buf1  = buf0  + ((size_t)4*RBf + 8)*rowEl;
    int nPxT = (W + 63) / 64;
    long zcGrid0 = ((long)4*RBf*2*256 + 2047)/2048;
    long zcGrid1 = ((long)4*RB1*2*256 + 2047)/2048;
    k_zcol<<<dim3((unsigned)zcGrid0), dim3(256), 0, stream>>>(buf0, Wp, RBf, W);
    k_zcol<<<dim3((unsigned)zcGrid1), dim3(256), 0, stream>>>(buf1, Wp, RB1, W);

    for (int r0 = 0; r0 < H; r0 += R){
      int r1 = (r0 + R < H) ? (r0 + R) : H;
      int Rc = r1 - r0;
      int ya0 = (r0-2 < 0) ? 0 : r0-2;
      int ya1 = (r1+2 > H) ? H : r1+2;
      int yb0 = (r0-1 < 0) ? 0 : r0-1;
      int yb1 = (r1+1 > H) ? H : r1+1;

      if (r0 == 0){
        long zg = ((long)4*2*Wp*256 + 2047)/2048;
        k_zrow<<<dim3((unsigned)zg), dim3(256), 0, stream>>>(buf0, (long)RBf*Wp*256, Wp, 0, 2);
        long zg1 = ((long)4*1*Wp*256 + 2047)/2048;
        k_zrow<<<dim3((unsigned)zg1), dim3(256), 0, stream>>>(buf1, (long)RB1*Wp*256, Wp, 0, 1);
      }
      if (r1 == H){
        long zg = ((long)4*2*Wp*256 + 2047)/2048;
        k_zrow<<<dim3((unsigned)zg), dim3(256), 0, stream>>>(buf0, (long)RBf*Wp*256, Wp, Rc+2, 2);
        long zg1 = ((long)4*1*Wp*256 + 2047)/2048;
        k_zrow<<<dim3((unsigned)zg1), dim3(256), 0, stream>>>(buf1, (long)RB1*Wp*256, Wp, Rc+1, 1);
      }

      k_trans<<<dim3(nPxT, ya1-ya0, 4), dim3(256), 0, stream>>>(
          feat[l], featT, H, W, Wp, ya0, ya0-(r0-2), RBf);

      // adapt: featT -> buf0, rows [ya0, ya1)
      k_conv6<1,false,false><<<dim3(nPxT, (ya1-ya0+1)/2, 4), dim3(256), 0, stream>>>(
          featT, wfA + (size_t)l*WFA_L, adapt_b + l*256, buf0,
          W, Wp, ya0, ya1, r0-2, RBf, r0-2, RBf,
          nullptr, nullptr, nullptr, 0);

      // conv1: buf0 -> buf1, rows [yb0, yb1)
      k_conv6<9,true,false><<<dim3(nPxT, (yb1-yb0+1)/2, 4), dim3(256), 0, stream>>>(
          buf0, wf1 + (size_t)l*WF3_L, biasc1 + l*256, buf1,
          W, Wp, yb0, yb1, r0-2, RBf, r0-1, RB1,
          nullptr, nullptr, nullptr, 0);

      // conv2 + fused pred: buf1 -> out, rows [r0, r1)
      k_conv6<9,true,true><<<dim3(nPxT, (Rc+1)/2, 4), dim3(256), 0, stream>>>(
          buf1, wf2 + (size_t)l*WF3_L, biasc2 + l*256, nullptr,
          W, Wp, r0, r1, r0-1, RB1, 0, 0,
          wfP + (size_t)l*WFP_L, bp + l*45, out + out_off, H);
    }
    out_off += (size_t)4*45*S;
  }
}

// Round 13
// 1537.591 us; speedup vs baseline: 1.1054x; 1.1054x over previous
//
#include <hip/hip_runtime.h>
#include <math.h>

typedef __attribute__((ext_vector_type(8))) short bf16x8;
typedef __attribute__((ext_vector_type(4))) float f32x4;
typedef __attribute__((ext_vector_type(4))) unsigned short us4;

#define EPSV 1e-5f

__device__ inline unsigned short f2bf(float f){
  unsigned u = __float_as_uint(f);
  u += 0x7fff + ((u>>16)&1);
  return (unsigned short)(u>>16);
}

// offset arg ALWAYS 0 (round-4 failure: imm-offset semantics ambiguous).
__device__ __forceinline__ void gload16(const unsigned short* g, char* l){
  __builtin_amdgcn_global_load_lds(
      (const __attribute__((address_space(1))) unsigned int*)g,
      (__attribute__((address_space(3))) unsigned int*)l, 16, 0, 0);
}

// ---------- feat NCHW fp32 -> featT NHWC bf16 (padded width Wp=W+2) ----------
__global__ __launch_bounds__(256) void k_trans(const float* __restrict__ feat,
    unsigned short* __restrict__ ft, int H, int W, int Wp, int y_begin,
    int slot_base, int RBf)
{
  int t = threadIdx.x;
  int lane = t & 63, wv = t >> 6;
  int x = blockIdx.x*64 + lane;
  int y = y_begin + blockIdx.y;
  int b = blockIdx.z;
  int slot = slot_base + blockIdx.y;
  if (x >= W) return;
  const float* fb = feat + ((size_t)(b*256)*H + y)*W + x;
  unsigned short* dst = ft + (((size_t)b*RBf + slot)*Wp + x + 1)*256;
  #pragma unroll 4
  for (int i=0;i<16;i++){
    int c0 = wv*4 + i*16;
    float v0 = fb[(size_t)(c0+0)*H*W];
    float v1 = fb[(size_t)(c0+1)*H*W];
    float v2 = fb[(size_t)(c0+2)*H*W];
    float v3 = fb[(size_t)(c0+3)*H*W];
    us4 o = { f2bf(v0), f2bf(v1), f2bf(v2), f2bf(v3) };
    *(us4*)(dst + c0) = o;
  }
}

// ---------- zero helpers ----------
__global__ __launch_bounds__(256) void k_zrow(unsigned short* __restrict__ buf,
    long bStr, int Wp, int slot0, int nslots)
{
  long i = ((long)blockIdx.x*256 + threadIdx.x)*8;
  long per_b = (long)nslots*Wp*256;
  if (i >= 4*per_b) return;
  int b = (int)(i / per_b); long r = i % per_b;
  unsigned short* d = buf + (size_t)b*bStr + (size_t)slot0*Wp*256 + r;
  us4 z = {0,0,0,0};
  *(us4*)d = z; *(us4*)(d+4) = z;
}

__global__ __launch_bounds__(256) void k_zcol(unsigned short* __restrict__ buf,
    int Wp, int RB, int W)
{
  long i = ((long)blockIdx.x*256 + threadIdx.x)*8;
  long tot = (long)4*RB*2*256;
  if (i >= tot) return;
  long u = i/8; int q = (int)(u & 31); int side = (int)((u>>5)&1);
  long bs = u>>6; int slot = (int)(bs % RB); int b = (int)(bs / RB);
  unsigned short* d = buf + (((size_t)b*RB + slot)*Wp + (side? W+1 : 0))*256 + q*8;
  us4 z = {0,0,0,0};
  *(us4*)d = z; *(us4*)(d+4) = z;
}

// ---------- weight repacks ----------
// w [L][co][ci][9] * BN scale -> [l][cb16][kc8][tap9][lane64][8] bf16
__global__ __launch_bounds__(256) void k_repack_conv(const float* __restrict__ w,
    const float* __restrict__ g, const float* __restrict__ v,
    unsigned short* __restrict__ wf)
{
  int t = blockIdx.x*256 + threadIdx.x;
  if (t >= 4*256*256) return;
  int ci = t & 255, co = (t>>8) & 255, l = t>>16;
  float s = g[l*256+co] * rsqrtf(v[l*256+co] + EPSV);
  const float* wp = w + (size_t)t*9;
  int cb = co>>4, kc = ci>>5;
  int lane = ((ci>>3)&3)*16 + (co&15);
  int e = ci&7;
  size_t base = (((size_t)(l*16+cb)*8 + kc)*9)*512 + (size_t)lane*8 + e;
  #pragma unroll
  for (int tap=0;tap<9;tap++)
    wf[base + (size_t)tap*512] = f2bf(wp[tap]*s);
}

// same layout, NO scale (raw w1 for the fold GEMM)
__global__ __launch_bounds__(256) void k_repack_conv_raw(const float* __restrict__ w,
    unsigned short* __restrict__ wf)
{
  int t = blockIdx.x*256 + threadIdx.x;
  if (t >= 4*256*256) return;
  int ci = t & 255, co = (t>>8) & 255, l = t>>16;
  const float* wp = w + (size_t)t*9;
  int cb = co>>4, kc = ci>>5;
  int lane = ((ci>>3)&3)*16 + (co&15);
  int e = ci&7;
  size_t base = (((size_t)(l*16+cb)*8 + kc)*9)*512 + (size_t)lane*8 + e;
  #pragma unroll
  for (int tap=0;tap<9;tap++)
    wf[base + (size_t)tap*512] = f2bf(wp[tap]);
}

// adapt_w [l][m][ci] -> B-fragments with N=ci, K=m:
// bawB[l][cit16][kc8][lane64][8]; ci = cit*16+(lane&15), m = kc*32+(lane>>4)*8+e
__global__ __launch_bounds__(256) void k_repack_awB(const float* __restrict__ aw,
    unsigned short* __restrict__ out)
{
  int t = blockIdx.x*256 + threadIdx.x;
  if (t >= 4*16*8*64) return;
  int lane = t & 63, kc = (t>>6)&7, cit = (t>>9)&15, l = t>>13;
  int ci = cit*16 + (lane&15);
  int m0 = kc*32 + ((lane>>4))*8;
  unsigned short tmp[8];
  #pragma unroll
  for (int e=0;e<8;e++)
    tmp[e] = f2bf(aw[ ((size_t)(l*256 + m0 + e))*256 + ci ]);
  unsigned short* d = out + (size_t)t*8;
  *(us4*)d = *(us4*)tmp; *(us4*)(d+4) = *(us4*)(tmp+4);
}

// fold GEMM: w1f[co,ci,tap] = s[co] * sum_m w1[co,m,tap]*aw[m,ci]
// A = w1raw frags [l][cb][kcm][tap][512]; B = bawB [l][cit][kcm][512]
// out: same fragment layout as k_repack_conv: [l][cb][kci][tap][512]
__global__ __launch_bounds__(256) void k_fold(
    const unsigned short* __restrict__ w1raw,
    const unsigned short* __restrict__ bawB,
    const float* __restrict__ g, const float* __restrict__ v,
    unsigned short* __restrict__ wf)
{
  int blk = blockIdx.x;              // l*36 + tap*4 + cich
  int cich = blk & 3;
  int tap  = (blk>>2) % 9;
  int l    = blk / 36;
  int tid = threadIdx.x, lane = tid&63, w = tid>>6;
  int l15 = lane&15, g4 = lane>>4;
  f32x4 acc[4][4];
  #pragma unroll
  for (int i=0;i<4;i++)
    #pragma unroll
    for (int j=0;j<4;j++) acc[i][j] = (f32x4){0.f,0.f,0.f,0.f};

  #pragma unroll 1
  for (int kc=0; kc<8; ++kc){
    bf16x8 A[4], B[4];
    #pragma unroll
    for (int cf=0;cf<4;cf++)
      A[cf] = *(const bf16x8*)(w1raw +
        ((((size_t)(l*16 + w*4+cf)*8 + kc)*9 + tap)*512) + (size_t)lane*8);
    #pragma unroll
    for (int pf=0;pf<4;pf++)
      B[pf] = *(const bf16x8*)(bawB +
        (((size_t)(l*16 + cich*4+pf)*8 + kc)*512) + (size_t)lane*8);
    #pragma unroll
    for (int cf=0;cf<4;cf++)
      #pragma unroll
      for (int pf=0;pf<4;pf++)
        acc[cf][pf] = __builtin_amdgcn_mfma_f32_16x16x32_bf16(A[cf], B[pf], acc[cf][pf], 0,0,0);
  }
  // scatter with BN scale into conv fragment layout
  #pragma unroll
  for (int cf=0;cf<4;cf++){
    #pragma unroll
    for (int pf=0;pf<4;pf++){
      int ci = cich*64 + pf*16 + l15;
      #pragma unroll
      for (int r=0;r<4;r++){
        int co = w*64 + cf*16 + g4*4 + r;
        float s = g[l*256+co] * rsqrtf(v[l*256+co] + EPSV);
        float val = acc[cf][pf][r] * s;
        int cb = co>>4, kci = ci>>5;
        int dlane = ((ci>>3)&3)*16 + (co&15);
        int e = ci&7;
        wf[ ((((size_t)(l*16+cb)*8 + kci)*9 + tap)*512) + (size_t)dlane*8 + e ] = f2bf(val);
      }
    }
  }
}

// pred 1x1 (45->pad48): [L][45][ci] -> [l][kc8][f3][lane64][8]
__global__ __launch_bounds__(192) void k_repack_pred(const float* __restrict__ w,
    unsigned short* __restrict__ wf)
{
  int t = blockIdx.x*192 + threadIdx.x;
  if (t >= 4*48*32) return;
  int o = t & 31, co = (t>>5)%48, l = t/1536;
  int ci0 = o*8, f = co>>4, kc = o>>2, lane = (o&3)*16 + (co&15);
  unsigned short* dst = wf + ((((size_t)l*8 + kc)*3 + f)*64 + lane)*8;
  #pragma unroll
  for (int e=0;e<8;e++){
    float val = (co<45) ? w[((size_t)(l*45+co)*256 + ci0 + e)] : 0.f;
    dst[e] = f2bf(val);
  }
}

// BN-folded bias (conv2): (b-m)*s + beta
__global__ __launch_bounds__(256) void k_bias(const float* __restrict__ b,
    const float* __restrict__ g, const float* __restrict__ be,
    const float* __restrict__ m, const float* __restrict__ v,
    float* __restrict__ out)
{
  int t = blockIdx.x*256 + threadIdx.x;
  if (t >= 1024) return;
  float s = g[t]*rsqrtf(v[t]+EPSV);
  out[t] = (b[t]-m[t])*s + be[t];
}

// conv1' 9-case border bias: bcase[l][yc*3+xc][co] =
//   be1 + s*(b1 - m1 + sum_{in-bounds taps} t[tap]),  t = w1 . adapt_b
__global__ __launch_bounds__(256) void k_bias1f(
    const float* __restrict__ w1, const float* __restrict__ ab,
    const float* __restrict__ b1, const float* __restrict__ g1,
    const float* __restrict__ be1, const float* __restrict__ m1,
    const float* __restrict__ v1, float* __restrict__ bcase)
{
  int t = blockIdx.x*256 + threadIdx.x;
  if (t >= 1024) return;
  int co = t & 255, l = t >> 8;
  float tt[9] = {0,0,0,0,0,0,0,0,0};
  const float* wp  = w1 + ((size_t)(l*256+co)*256)*9;
  const float* abp = ab + l*256;
  for (int m=0;m<256;m++){
    float a = abp[m];
    const float* w9 = wp + (size_t)m*9;
    #pragma unroll
    for (int tap=0;tap<9;tap++) tt[tap] += w9[tap]*a;
  }
  float s = g1[t]*rsqrtf(v1[t]+EPSV);
  float base = be1[t] + s*(b1[t]-m1[t]);
  for (int yc=0;yc<3;yc++)
    for (int xc=0;xc<3;xc++){
      float sum = 0.f;
      #pragma unroll
      for (int tap=0;tap<9;tap++){
        int ky = tap/3, kx = tap%3;
        bool oob = (yc==0&&ky==0)||(yc==2&&ky==2)||(xc==0&&kx==0)||(xc==2&&kx==2);
        if (!oob) sum += tt[tap];
      }
      bcase[ ((size_t)(l*9) + yc*3+xc)*256 + co ] = base + s*sum;
    }
}

// ---------- MFMA conv: 256co x 2rows x 64px per block, 4 waves ----------
// wave = 64co (cf=4) x 64px x BOTH rows (acc0/acc1, 128 AGPR) -- no A dup.
// R10 schedule (measured best): double-buffered LDS, stage(next)->compute->
// __syncthreads per kc, no inline asm.
// FOLD: conv1-folded-with-adapt; bias comes from 9-case border table.
// PRED: conv2 keeps x2 in LDS and runs the 45-co pred GEMM + activations.
template<int TAPS, bool RELU, bool PRED, bool FOLD>
__global__ __launch_bounds__(256,2) void k_conv6(
    const unsigned short* __restrict__ in, const unsigned short* __restrict__ wf,
    const float* __restrict__ bias, unsigned short* __restrict__ outb,
    int W, int Wp, int y_begin, int y_end, int in_row0, int RBin,
    int out_row0, int RBout,
    const unsigned short* __restrict__ wfP, const float* __restrict__ bp,
    float* __restrict__ outP, int H)
{
  constexpr bool T9    = (TAPS==9);
  constexpr int ROWS   = T9 ? 4 : 2;
  constexpr int PXS    = T9 ? 72 : 64;
  constexpr int RSTR   = PXS*64;
  constexpr int BUFB   = ROWS*RSTR;        // 18432
  constexpr int NCHK   = BUFB/1024;        // 18
  constexpr int NFULL  = NCHK/4;
  constexpr int NTAIL  = NCHK - NFULL*4;
  constexpr int CPW    = NFULL + (NTAIL?1:0);
  constexpr int PERROW = PXS*4;
  constexpr int LDSB   = PRED ? (2*BUFB > 65536 ? 2*BUFB : 65536) : 2*BUFB;
  __shared__ __align__(1024) char lds[LDSB];

  int tid = threadIdx.x, lane = tid&63, w = tid>>6;
  int l15 = lane&15, g4 = lane>>4;
  int x0 = blockIdx.x*64;
  int y0 = y_begin + 2*blockIdx.y;
  int b  = blockIdx.z;

  size_t rowEl = (size_t)Wp*256;
  const unsigned short* gb =
      in + ((size_t)b*RBin + (y0-1-in_row0))*rowEl + (size_t)x0*256;

  int Poff[CPW], Coff[CPW];
  #pragma unroll
  for (int i=0;i<CPW;i++){
    int c = (i<NFULL) ? (4*i + w) : (4*NFULL + w);
    int s = c*64 + lane;
    int r = s / PERROW;
    int rem = s - r*PERROW;
    int px = rem>>2, sq = rem&3;
    int slot = sq ^ (px&3) ^ ((px>>2)&3);
    Poff[i] = r*(int)rowEl + px*256 + slot*8;
    Coff[i] = c*1024;
  }

  int vb[12];
  #pragma unroll
  for (int kx=0;kx<3;kx++)
    #pragma unroll
    for (int pf=0;pf<4;pf++){
      int px = pf*16 + l15 + kx;
      vb[kx*4+pf] = px*64 + ((g4 ^ (px&3) ^ ((px>>2)&3))<<4);
    }

  const unsigned short* wA = wf + (size_t)(w*4)*(8*TAPS*512) + (size_t)lane*8;

  f32x4 acc0[4][4], acc1[4][4];
  #pragma unroll
  for (int i=0;i<4;i++)
    #pragma unroll
    for (int j=0;j<4;j++){
      acc0[i][j] = (f32x4){0.f,0.f,0.f,0.f};
      acc1[i][j] = (f32x4){0.f,0.f,0.f,0.f};
    }

  const unsigned short* gbk = gb;
  auto stage = [&](int jb){
    #pragma unroll
    for (int i=0;i<NFULL;i++) gload16(gbk + Poff[i], (char*)&lds[0] + jb + Coff[i]);
    if constexpr (NTAIL > 0){
      if (w < NTAIL) gload16(gbk + Poff[NFULL], (char*)&lds[0] + jb + Coff[NFULL]);
    }
    gbk += 32;
  };

#define LOADB(KY, KX, BV) { \
  _Pragma("unroll") \
  for (int pf=0;pf<4;pf++) BV[pf] = *(const bf16x8*)(base + (KY)*RSTR + vb[(KX)*4+pf]); }

#define LOADA(G, AV) { \
  _Pragma("unroll") \
  for (int cf=0;cf<4;cf++) AV[cf] = *(const bf16x8*)(wk + (size_t)cf*(8*TAPS*512) + (G)*512); }

#define MM(AC, AV, BV) { \
  _Pragma("unroll") for (int cf=0;cf<4;cf++) \
  _Pragma("unroll") for (int pf=0;pf<4;pf++) \
    AC[cf][pf] = __builtin_amdgcn_mfma_f32_16x16x32_bf16(AV[cf], BV[pf], AC[cf][pf], 0,0,0); }

  auto compute = [&](int kc, const char* base){
    const unsigned short* wk = wA + (size_t)kc*(TAPS*512);
    bf16x8 A[4], B0[4], B1[4];
    #pragma unroll
    for (int kx=0;kx<3;kx++){
      LOADB(0,kx,B0) LOADB(1,kx,B1)
      LOADA(0*3+kx,A) MM(acc0,A,B0) MM(acc1,A,B1)
      LOADB(2,kx,B0)
      LOADA(1*3+kx,A) MM(acc0,A,B1) MM(acc1,A,B0)
      LOADB(3,kx,B1)
      LOADA(2*3+kx,A) MM(acc0,A,B0) MM(acc1,A,B1)
    }
  };

  // R10 double-buffer pipeline
  stage(0);
  __syncthreads();
  #pragma unroll 1
  for (int kt=0; kt<4; ++kt){
    stage(BUFB);
    compute(2*kt, (const char*)&lds[0]);
    __syncthreads();
    if (kt < 3) stage(0);
    compute(2*kt+1, (const char*)&lds[0] + BUFB);
    __syncthreads();
  }
#undef LOADB
#undef LOADA
#undef MM

  if constexpr (!PRED){
    bool ok1 = (y0 + 1) < y_end;
    int oslot = y0 - out_row0;
    unsigned short* ob = outb + ((size_t)b*RBout + oslot)*rowEl + 256;
    int yc0 = 1, yc1 = 1;
    if constexpr (FOLD){
      yc0 = (y0==0)?0:((y0==H-1)?2:1);
      yc1 = (y0+1==0)?0:((y0+1==H-1)?2:1);
    }
    #pragma unroll
    for (int cf=0; cf<4; ++cf){
      int co0 = w*64 + cf*16 + g4*4;
      f32x4 bbI = *(const f32x4*)(bias + (FOLD ? 4*256 : 0) + co0); // interior
      #pragma unroll
      for (int pf=0; pf<4; ++pf){
        int x = x0 + pf*16 + l15;
        if (x < W){
          f32x4 b0 = bbI, b1v = bbI;
          if constexpr (FOLD){
            int xc = (x==0)?0:((x==W-1)?2:1);
            b0  = *(const f32x4*)(bias + (yc0*3+xc)*256 + co0);
            b1v = *(const f32x4*)(bias + (yc1*3+xc)*256 + co0);
          }
          float v0 = acc0[cf][pf][0]+b0[0], v1 = acc0[cf][pf][1]+b0[1];
          float v2 = acc0[cf][pf][2]+b0[2], v3 = acc0[cf][pf][3]+b0[3];
          if (RELU){ v0=fmaxf(v0,0.f); v1=fmaxf(v1,0.f); v2=fmaxf(v2,0.f); v3=fmaxf(v3,0.f); }
          us4 o = { f2bf(v0), f2bf(v1), f2bf(v2), f2bf(v3) };
          *(us4*)(ob + (size_t)x*256 + co0) = o;
          if (ok1){
            float u0 = acc1[cf][pf][0]+b1v[0], u1 = acc1[cf][pf][1]+b1v[1];
            float u2 = acc1[cf][pf][2]+b1v[2], u3 = acc1[cf][pf][3]+b1v[3];
            if (RELU){ u0=fmaxf(u0,0.f); u1=fmaxf(u1,0.f); u2=fmaxf(u2,0.f); u3=fmaxf(u3,0.f); }
            us4 o1 = { f2bf(u0), f2bf(u1), f2bf(u2), f2bf(u3) };
            *(us4*)(ob + rowEl + (size_t)x*256 + co0) = o1;
          }
        }
      }
    }
  } else {
    // all waves done reading staging buffers before xs overwrites lds
    __syncthreads();
    // fused pred: x2 -> swizzled LDS tile [2][64px][32 slots][16B]
    unsigned short* xs = (unsigned short*)&lds[0];
    #pragma unroll
    for (int cf=0; cf<4; ++cf){
      int co0 = w*64 + cf*16 + g4*4;
      f32x4 bb = *(const f32x4*)(bias + co0);
      int c16 = co0 >> 3;
      int sub = (g4 & 1) * 8;
      #pragma unroll
      for (int pf=0; pf<4; ++pf){
        int px = pf*16 + l15;
        int slot = c16 ^ (px & 31);
        float v0 = fmaxf(acc0[cf][pf][0]+bb[0],0.f), v1 = fmaxf(acc0[cf][pf][1]+bb[1],0.f);
        float v2 = fmaxf(acc0[cf][pf][2]+bb[2],0.f), v3 = fmaxf(acc0[cf][pf][3]+bb[3],0.f);
        us4 o0 = { f2bf(v0), f2bf(v1), f2bf(v2), f2bf(v3) };
        *(us4*)((char*)xs + ((px*32 + slot)<<4) + sub) = o0;
        float u0 = fmaxf(acc1[cf][pf][0]+bb[0],0.f), u1 = fmaxf(acc1[cf][pf][1]+bb[1],0.f);
        float u2 = fmaxf(acc1[cf][pf][2]+bb[2],0.f), u3 = fmaxf(acc1[cf][pf][3]+bb[3],0.f);
        us4 o1 = { f2bf(u0), f2bf(u1), f2bf(u2), f2bf(u3) };
        *(us4*)((char*)xs + 32768 + ((px*32 + slot)<<4) + sub) = o1;
      }
    }
    __syncthreads();

    int rw2 = w & 1, pxg = w >> 1;
    f32x4 ap[3][2];
    #pragma unroll
    for (int f=0;f<3;f++){ ap[f][0] = (f32x4){0,0,0,0}; ap[f][1] = (f32x4){0,0,0,0}; }
    #pragma unroll
    for (int kc=0;kc<8;kc++){
      bf16x8 Bf[2];
      #pragma unroll
      for (int t2=0;t2<2;t2++){
        int px = (pxg*2+t2)*16 + l15;
        int slot = (kc*4 + g4) ^ (px & 31);
        Bf[t2] = *(const bf16x8*)((char*)xs + rw2*32768 + ((px*32 + slot)<<4));
      }
      #pragma unroll
      for (int f=0;f<3;f++){
        bf16x8 Af = *(const bf16x8*)(wfP + (((size_t)kc*3 + f)*64 + lane)*8);
        ap[f][0] = __builtin_amdgcn_mfma_f32_16x16x32_bf16(Af, Bf[0], ap[f][0], 0,0,0);
        ap[f][1] = __builtin_amdgcn_mfma_f32_16x16x32_bf16(Af, Bf[1], ap[f][1], 0,0,0);
      }
    }
    int y = y0 + rw2;
    if (y < y_end){
      size_t S = (size_t)H*W;
      #pragma unroll
      for (int f=0;f<3;f++){
        #pragma unroll
        for (int t2=0;t2<2;t2++){
          int px = x0 + (pxg*2+t2)*16 + l15;
          if (px < W){
            #pragma unroll
            for (int r=0;r<4;r++){
              int co = f*16 + g4*4 + r;
              if (co < 45){
                float val = ap[f][t2][r] + bp[co];
                int a_idx = co/15, c = co%15;
                int cum,c0,n;
                if (c<4)       {cum=0;c0=0;n=4;}
                else if (c==4) {cum=4;c0=4;n=1;}
                else if (c<10) {cum=5;c0=5;n=5;}
                else if (c<14) {cum=10;c0=10;n=4;}
                else           {cum=14;c0=14;n=1;}
                if (c==4) val = 1.f/(1.f+expf(-val));
                else if (c==14) val = (val>20.f? val : log1pf(expf(val))) + 1.f;
                size_t chan = ((size_t)(12*cum) + (size_t)((b*3+a_idx)*n + (c-c0)))*S;
                outP[chan + (size_t)y*W + px] = val;
              }
            }
          }
        }
      }
    }
  }
}

// ---------- host ----------
extern "C" void kernel_launch(void* const* d_in, const int* in_sizes, int n_in,
                              void* d_out, int out_size, void* d_ws, size_t ws_size,
                              hipStream_t stream)
{
  static const int Hs[4] = {192,96,48,24};
  static const int Wd[4] = {320,160,80,40};
  const float* feat[4] = {(const float*)d_in[0],(const float*)d_in[1],
                          (const float*)d_in[2],(const float*)d_in[3]};
  const float* adapt_w = (const float*)d_in[4];
  const float* adapt_b = (const float*)d_in[5];
  const float* w1 = (const float*)d_in[6];  const float* b1 = (const float*)d_in[7];
  const float* g1 = (const float*)d_in[8];  const float* be1= (const float*)d_in[9];
  const float* m1 = (const float*)d_in[10]; const float* v1 = (const float*)d_in[11];
  const float* w2 = (const float*)d_in[12]; const float* b2 = (const float*)d_in[13];
  const float* g2 = (const float*)d_in[14]; const float* be2= (const float*)d_in[15];
  const float* m2 = (const float*)d_in[16]; const float* v2 = (const float*)d_in[17];
  const float* wp = (const float*)d_in[18]; const float* bp = (const float*)d_in[19];
  float* out = (float*)d_out;

  char* base = (char*)d_ws;
  size_t off = 0;
  auto alloc = [&](size_t bytes)->char*{
    char* p = base + off; off = (off + bytes + 255) & ~(size_t)255; return p; };

  const size_t WF3_L = (size_t)16*8*9*512;   // per-level elems, 3x3 frag layout
  const size_t WAB_L = (size_t)16*8*512;     // per-level elems, adapt B-frags
  const size_t WFP_L = (size_t)8*3*512;
  unsigned short* wf1raw = (unsigned short*)alloc(4*WF3_L*2);
  unsigned short* bawB   = (unsigned short*)alloc(4*WAB_L*2);
  unsigned short* wf1f   = (unsigned short*)alloc(4*WF3_L*2);
  unsigned short* wf2    = (unsigned short*)alloc(4*WF3_L*2);
  unsigned short* wfP    = (unsigned short*)alloc(4*WFP_L*2);
  float* bcase1 = (float*)alloc(4*9*256*4);
  float* biasc2 = (float*)alloc(1024*4);
  char*  bufbase = base + off;
  size_t rem = (ws_size > off + 65536) ? (ws_size - off - 65536) : 0;

  k_repack_conv_raw<<<dim3(1024), dim3(256), 0, stream>>>(w1, wf1raw);
  k_repack_awB     <<<dim3(128),  dim3(256), 0, stream>>>(adapt_w, bawB);
  k_repack_conv    <<<dim3(1024), dim3(256), 0, stream>>>(w2, g2, v2, wf2);
  k_repack_pred    <<<dim3(32),   dim3(192), 0, stream>>>(wp, wfP);
  k_bias1f<<<dim3(4), dim3(256), 0, stream>>>(w1, adapt_b, b1, g1, be1, m1, v1, bcase1);
  k_bias  <<<dim3(4), dim3(256), 0, stream>>>(b2, g2, be2, m2, v2, biasc2);
  k_fold  <<<dim3(144), dim3(256), 0, stream>>>(wf1raw, bawB, g1, v1, wf1f);

  size_t out_off = 0;
  for (int l=0;l<4;l++){
    int H = Hs[l], W = Wd[l], Wp = W + 2;
    size_t S = (size_t)H*W;
    size_t rowEl = (size_t)Wp*256;
    long slotsAvail = (long)(rem / (rowEl*2));
    long Rl = (slotsAvail - 60) / 8;           // featT(R+4)+buf1(R+2), 4 batches
    int R = (int)(Rl < 2 ? 2 : (Rl > H ? (long)H : Rl));
    int RBf = R + 4, RB1 = R + 2;
    unsigned short* featT = (unsigned short*)bufbase;
    unsigned short* buf1  = featT + ((size_t)4*RBf + 8)*rowEl;
    int nPxT = (W + 63) / 64;
    long zcGrid0 = ((long)4*RBf*2*256 + 2047)/2048;
    long zcGrid1 = ((long)4*RB1*2*256 + 2047)/2048;
    k_zcol<<<dim3((unsigned)zcGrid0), dim3(256), 0, stream>>>(featT, Wp, RBf, W);
    k_zcol<<<dim3((unsigned)zcGrid1), dim3(256), 0, stream>>>(buf1, Wp, RB1, W);

    for (int r0 = 0; r0 < H; r0 += R){
      int r1 = (r0 + R < H) ? (r0 + R) : H;
      int Rc = r1 - r0;
      int ya0 = (r0-2 < 0) ? 0 : r0-2;
      int ya1 = (r1+2 > H) ? H : r1+2;
      int yb0 = (r0-1 < 0) ? 0 : r0-1;
      int yb1 = (r1+1 > H) ? H : r1+1;

      if (r0 == 0){
        long zg = ((long)4*2*Wp*256 + 2047)/2048;
        k_zrow<<<dim3((unsigned)zg), dim3(256), 0, stream>>>(featT, (long)RBf*Wp*256, Wp, 0, 2);
        long zg1 = ((long)4*1*Wp*256 + 2047)/2048;
        k_zrow<<<dim3((unsigned)zg1), dim3(256), 0, stream>>>(buf1, (long)RB1*Wp*256, Wp, 0, 1);
      }
      if (r1 == H){
        long zg = ((long)4*2*Wp*256 + 2047)/2048;
        k_zrow<<<dim3((unsigned)zg), dim3(256), 0, stream>>>(featT, (long)RBf*Wp*256, Wp, Rc+2, 2);
        long zg1 = ((long)4*1*Wp*256 + 2047)/2048;
        k_zrow<<<dim3((unsigned)zg1), dim3(256), 0, stream>>>(buf1, (long)RB1*Wp*256, Wp, Rc+1, 1);
      }

      k_trans<<<dim3(nPxT, ya1-ya0, 4), dim3(256), 0, stream>>>(
          feat[l], featT, H, W, Wp, ya0, ya0-(r0-2), RBf);

      // conv1' (adapt folded in): featT -> buf1, rows [yb0, yb1)
      k_conv6<9,true,false,true><<<dim3(nPxT, (yb1-yb0+1)/2, 4), dim3(256), 0, stream>>>(
          featT, wf1f + (size_t)l*WF3_L, bcase1 + (size_t)l*9*256, buf1,
          W, Wp, yb0, yb1, r0-2, RBf, r0-1, RB1,
          nullptr, nullptr, nullptr, H);

      // conv2 + fused pred: buf1 -> out, rows [r0, r1)
      k_conv6<9,true,true,false><<<dim3(nPxT, (Rc+1)/2, 4), dim3(256), 0, stream>>>(
          buf1, wf2 + (size_t)l*WF3_L, biasc2 + l*256, nullptr,
          W, Wp, r0, r1, r0-1, RB1, 0, 0,
          wfP + (size_t)l*WFP_L, bp + l*45, out + out_off, H);
    }
    out_off += (size_t)4*45*S;
  }
}

// Round 14
// 1260.662 us; speedup vs baseline: 1.3482x; 1.2197x over previous
//
#include <hip/hip_runtime.h>
#include <math.h>

typedef __attribute__((ext_vector_type(8))) short bf16x8;
typedef __attribute__((ext_vector_type(4))) float f32x4;
typedef __attribute__((ext_vector_type(4))) unsigned short us4;

#define EPSV 1e-5f

__device__ inline unsigned short f2bf(float f){
  unsigned u = __float_as_uint(f);
  u += 0x7fff + ((u>>16)&1);
  return (unsigned short)(u>>16);
}

__device__ __forceinline__ void gload16(const unsigned short* g, char* l){
  __builtin_amdgcn_global_load_lds(
      (const __attribute__((address_space(1))) unsigned int*)g,
      (__attribute__((address_space(3))) unsigned int*)l, 16, 0, 0);
}

// ======== param structs for fused-grid launches ========
struct TrP {
  int cum[5];
  int W[4], Wp[4], H[4], nPx[4];
  unsigned long long ftOff[4];
};
struct CvP {
  int cum[5];
  int W[4], Wp[4], H[4], nPx[4], nRows[4];
  unsigned long long inOff[4], outOff[4], outPOff[4];
};
#define NZJOB 32
struct ZTab {
  unsigned long long off[NZJOB];
  unsigned long long cum[NZJOB+1];   // in 8-elem stores
  int rowLen[NZJOB];                 // elems, multiple of 8
  int rowStride[NZJOB];              // elems
};

// ======== fused border-zero ========
__global__ __launch_bounds__(256) void k_zeroB(unsigned short* ws, ZTab T){
  long long idx = (long long)blockIdx.x*256 + threadIdx.x;
  if (idx >= (long long)T.cum[NZJOB]) return;
  int j = 0;
  #pragma unroll
  for (int k=1;k<NZJOB;k++) j += (idx >= (long long)T.cum[k]);
  long long r = idx - (long long)T.cum[j];
  int spr = T.rowLen[j] >> 3;
  int row = (int)(r / spr), c = (int)(r % spr);
  unsigned short* d = ws + T.off[j] + (size_t)row*T.rowStride[j] + (size_t)c*8;
  us4 z = {0,0,0,0};
  *(us4*)d = z; *(us4*)(d+4) = z;
}

// ======== fused trans: NCHW fp32 -> padded NHWC bf16, all levels ========
__global__ __launch_bounds__(256) void k_transF(const float* __restrict__ f0,
    const float* __restrict__ f1, const float* __restrict__ f2,
    const float* __restrict__ f3, unsigned short* __restrict__ ws, TrP P)
{
  int bx = blockIdx.x;
  int l = (bx>=P.cum[1]) + (bx>=P.cum[2]) + (bx>=P.cum[3]);
  int r = bx - P.cum[l];
  int nPx = P.nPx[l];
  int pxt = r % nPx; r /= nPx;
  int H = P.H[l];
  int y = r % H; int b = r / H;
  int W = P.W[l], Wp = P.Wp[l];
  const float* feat = (l==0)?f0:(l==1)?f1:(l==2)?f2:f3;
  int t = threadIdx.x, lane = t & 63, wv = t >> 6;
  int x = pxt*64 + lane;
  if (x >= W) return;
  const float* fb = feat + ((size_t)(b*256)*H + y)*W + x;
  unsigned short* dst = ws + P.ftOff[l] + (((size_t)b*(H+4) + (y+2))*Wp + x + 1)*256;
  #pragma unroll 4
  for (int i=0;i<16;i++){
    int c0 = wv*4 + i*16;
    float v0 = fb[(size_t)(c0+0)*H*W];
    float v1 = fb[(size_t)(c0+1)*H*W];
    float v2 = fb[(size_t)(c0+2)*H*W];
    float v3 = fb[(size_t)(c0+3)*H*W];
    us4 o = { f2bf(v0), f2bf(v1), f2bf(v2), f2bf(v3) };
    *(us4*)(dst + c0) = o;
  }
}

// ======== fused conv (all levels in one grid) ========
// PRED=false: conv1' (adapt-folded weights, 9-case border bias) featT->buf1
// PRED=true : conv2 + fused pred head, buf1 -> sectioned NCHW fp32 out
template<bool PRED>
__global__ __launch_bounds__(256,2) void k_convF(
    unsigned short* __restrict__ ws, CvP P,
    const unsigned short* __restrict__ wfB, const float* __restrict__ biasB,
    const unsigned short* __restrict__ wfPB, const float* __restrict__ bpB,
    float* __restrict__ outB)
{
  constexpr int ROWS   = 4;
  constexpr int PXS    = 72;
  constexpr int RSTR   = PXS*64;
  constexpr int BUFB   = ROWS*RSTR;        // 18432
  constexpr int NCHK   = BUFB/1024;        // 18
  constexpr int NFULL  = NCHK/4;           // 4
  constexpr int NTAIL  = NCHK - NFULL*4;   // 2
  constexpr int CPW    = NFULL + 1;
  constexpr int PERROW = PXS*4;
  constexpr int LDSB   = PRED ? 65536 : 2*BUFB;
  __shared__ __align__(1024) char lds[LDSB];

  int bx = blockIdx.x;
  int l = (bx>=P.cum[1]) + (bx>=P.cum[2]) + (bx>=P.cum[3]);
  int r = bx - P.cum[l];
  int nPx = P.nPx[l];
  int pxt = r % nPx; r /= nPx;
  int nR = P.nRows[l];
  int row = r % nR; int b = r / nR;
  int W = P.W[l], Wp = P.Wp[l], H = P.H[l];
  int RBin = H + (PRED ? 2 : 4);
  int y0 = 2*row;

  const unsigned short* in = ws + P.inOff[l];
  const unsigned short* wf = wfB + (size_t)l*((size_t)16*8*9*512);
  const float* bias = biasB + (size_t)l*(PRED ? 256 : 9*256);

  int tid = threadIdx.x, lane = tid&63, w = tid>>6;
  int l15 = lane&15, g4 = lane>>4;
  int x0 = pxt*64;

  size_t rowEl = (size_t)Wp*256;
  // in_row0 = PRED ? -1 : -2 ; staged top row = y0-1  -> offset rows:
  const unsigned short* gb =
      in + ((size_t)b*RBin + (size_t)(PRED ? y0 : y0+1))*rowEl + (size_t)x0*256;

  int Poff[CPW], Coff[CPW];
  #pragma unroll
  for (int i=0;i<CPW;i++){
    int c = (i<NFULL) ? (4*i + w) : (4*NFULL + w);
    int s = c*64 + lane;
    int rr = s / PERROW;
    int rem = s - rr*PERROW;
    int px = rem>>2, sq = rem&3;
    int slot = sq ^ (px&3) ^ ((px>>2)&3);
    Poff[i] = rr*(int)rowEl + px*256 + slot*8;
    Coff[i] = c*1024;
  }

  int vb[12];
  #pragma unroll
  for (int kx=0;kx<3;kx++)
    #pragma unroll
    for (int pf=0;pf<4;pf++){
      int px = pf*16 + l15 + kx;
      vb[kx*4+pf] = px*64 + ((g4 ^ (px&3) ^ ((px>>2)&3))<<4);
    }

  const unsigned short* wA = wf + (size_t)(w*4)*(8*9*512) + (size_t)lane*8;

  f32x4 acc0[4][4], acc1[4][4];
  #pragma unroll
  for (int i=0;i<4;i++)
    #pragma unroll
    for (int j=0;j<4;j++){
      acc0[i][j] = (f32x4){0.f,0.f,0.f,0.f};
      acc1[i][j] = (f32x4){0.f,0.f,0.f,0.f};
    }

  const unsigned short* gbk = gb;
  auto stage = [&](int jb){
    #pragma unroll
    for (int i=0;i<NFULL;i++) gload16(gbk + Poff[i], (char*)&lds[0] + jb + Coff[i]);
    if (w < NTAIL) gload16(gbk + Poff[NFULL], (char*)&lds[0] + jb + Coff[NFULL]);
    gbk += 32;
  };

#define LOADB(KY, KX, BV) { \
  _Pragma("unroll") \
  for (int pf=0;pf<4;pf++) BV[pf] = *(const bf16x8*)(base + (KY)*RSTR + vb[(KX)*4+pf]); }

#define LOADA(G, AV) { \
  _Pragma("unroll") \
  for (int cf=0;cf<4;cf++) AV[cf] = *(const bf16x8*)(wk + (size_t)cf*(8*9*512) + (G)*512); }

#define MM(AC, AV, BV) { \
  _Pragma("unroll") for (int cf=0;cf<4;cf++) \
  _Pragma("unroll") for (int pf=0;pf<4;pf++) \
    AC[cf][pf] = __builtin_amdgcn_mfma_f32_16x16x32_bf16(AV[cf], BV[pf], AC[cf][pf], 0,0,0); }

  auto compute = [&](int kc, const char* base){
    const unsigned short* wk = wA + (size_t)kc*(9*512);
    bf16x8 A[4], B0[4], B1[4];
    #pragma unroll
    for (int kx=0;kx<3;kx++){
      LOADB(0,kx,B0) LOADB(1,kx,B1)
      LOADA(0*3+kx,A) MM(acc0,A,B0) MM(acc1,A,B1)
      LOADB(2,kx,B0)
      LOADA(1*3+kx,A) MM(acc0,A,B1) MM(acc1,A,B0)
      LOADB(3,kx,B1)
      LOADA(2*3+kx,A) MM(acc0,A,B0) MM(acc1,A,B1)
    }
  };

  stage(0);
  __syncthreads();
  #pragma unroll 1
  for (int kt=0; kt<4; ++kt){
    stage(BUFB);
    compute(2*kt, (const char*)&lds[0]);
    __syncthreads();
    if (kt < 3) stage(0);
    compute(2*kt+1, (const char*)&lds[0] + BUFB);
    __syncthreads();
  }
#undef LOADB
#undef LOADA
#undef MM

  if constexpr (!PRED){
    // conv1' epilogue: 9-case border bias + ReLU, bf16 NHWC store
    bool ok1 = (y0 + 1) < H;
    unsigned short* ob = ws + P.outOff[l] + ((size_t)b*(H+2) + (y0+1))*rowEl + 256;
    int yc0 = (y0==0)?0:((y0==H-1)?2:1);
    int yc1 = (y0+1==0)?0:((y0+1==H-1)?2:1);
    #pragma unroll
    for (int cf=0; cf<4; ++cf){
      int co0 = w*64 + cf*16 + g4*4;
      #pragma unroll
      for (int pf=0; pf<4; ++pf){
        int x = x0 + pf*16 + l15;
        if (x < W){
          int xc = (x==0)?0:((x==W-1)?2:1);
          f32x4 b0  = *(const f32x4*)(bias + (yc0*3+xc)*256 + co0);
          f32x4 b1v = *(const f32x4*)(bias + (yc1*3+xc)*256 + co0);
          float v0 = fmaxf(acc0[cf][pf][0]+b0[0],0.f), v1 = fmaxf(acc0[cf][pf][1]+b0[1],0.f);
          float v2 = fmaxf(acc0[cf][pf][2]+b0[2],0.f), v3 = fmaxf(acc0[cf][pf][3]+b0[3],0.f);
          us4 o = { f2bf(v0), f2bf(v1), f2bf(v2), f2bf(v3) };
          *(us4*)(ob + (size_t)x*256 + co0) = o;
          if (ok1){
            float u0 = fmaxf(acc1[cf][pf][0]+b1v[0],0.f), u1 = fmaxf(acc1[cf][pf][1]+b1v[1],0.f);
            float u2 = fmaxf(acc1[cf][pf][2]+b1v[2],0.f), u3 = fmaxf(acc1[cf][pf][3]+b1v[3],0.f);
            us4 o1 = { f2bf(u0), f2bf(u1), f2bf(u2), f2bf(u3) };
            *(us4*)(ob + rowEl + (size_t)x*256 + co0) = o1;
          }
        }
      }
    }
  } else {
    __syncthreads();
    unsigned short* xs = (unsigned short*)&lds[0];
    #pragma unroll
    for (int cf=0; cf<4; ++cf){
      int co0 = w*64 + cf*16 + g4*4;
      f32x4 bb = *(const f32x4*)(bias + co0);
      int c16 = co0 >> 3;
      int sub = (g4 & 1) * 8;
      #pragma unroll
      for (int pf=0; pf<4; ++pf){
        int px = pf*16 + l15;
        int slot = c16 ^ (px & 31);
        float v0 = fmaxf(acc0[cf][pf][0]+bb[0],0.f), v1 = fmaxf(acc0[cf][pf][1]+bb[1],0.f);
        float v2 = fmaxf(acc0[cf][pf][2]+bb[2],0.f), v3 = fmaxf(acc0[cf][pf][3]+bb[3],0.f);
        us4 o0 = { f2bf(v0), f2bf(v1), f2bf(v2), f2bf(v3) };
        *(us4*)((char*)xs + ((px*32 + slot)<<4) + sub) = o0;
        float u0 = fmaxf(acc1[cf][pf][0]+bb[0],0.f), u1 = fmaxf(acc1[cf][pf][1]+bb[1],0.f);
        float u2 = fmaxf(acc1[cf][pf][2]+bb[2],0.f), u3 = fmaxf(acc1[cf][pf][3]+bb[3],0.f);
        us4 o1 = { f2bf(u0), f2bf(u1), f2bf(u2), f2bf(u3) };
        *(us4*)((char*)xs + 32768 + ((px*32 + slot)<<4) + sub) = o1;
      }
    }
    __syncthreads();

    const unsigned short* wfP = wfPB + (size_t)l*((size_t)8*3*512);
    const float* bp = bpB + l*45;
    float* outP = outB + P.outPOff[l];
    int rw2 = w & 1, pxg = w >> 1;
    f32x4 ap[3][2];
    #pragma unroll
    for (int f=0;f<3;f++){ ap[f][0] = (f32x4){0,0,0,0}; ap[f][1] = (f32x4){0,0,0,0}; }
    #pragma unroll
    for (int kc=0;kc<8;kc++){
      bf16x8 Bf[2];
      #pragma unroll
      for (int t2=0;t2<2;t2++){
        int px = (pxg*2+t2)*16 + l15;
        int slot = (kc*4 + g4) ^ (px & 31);
        Bf[t2] = *(const bf16x8*)((char*)xs + rw2*32768 + ((px*32 + slot)<<4));
      }
      #pragma unroll
      for (int f=0;f<3;f++){
        bf16x8 Af = *(const bf16x8*)(wfP + (((size_t)kc*3 + f)*64 + lane)*8);
        ap[f][0] = __builtin_amdgcn_mfma_f32_16x16x32_bf16(Af, Bf[0], ap[f][0], 0,0,0);
        ap[f][1] = __builtin_amdgcn_mfma_f32_16x16x32_bf16(Af, Bf[1], ap[f][1], 0,0,0);
      }
    }
    int y = y0 + rw2;
    if (y < H){
      size_t S = (size_t)H*W;
      #pragma unroll
      for (int f=0;f<3;f++){
        #pragma unroll
        for (int t2=0;t2<2;t2++){
          int px = x0 + (pxg*2+t2)*16 + l15;
          if (px < W){
            #pragma unroll
            for (int rr=0;rr<4;rr++){
              int co = f*16 + g4*4 + rr;
              if (co < 45){
                float val = ap[f][t2][rr] + bp[co];
                int a_idx = co/15, c = co%15;
                int cum,c0,n;
                if (c<4)       {cum=0;c0=0;n=4;}
                else if (c==4) {cum=4;c0=4;n=1;}
                else if (c<10) {cum=5;c0=5;n=5;}
                else if (c<14) {cum=10;c0=10;n=4;}
                else           {cum=14;c0=14;n=1;}
                if (c==4) val = 1.f/(1.f+expf(-val));
                else if (c==14) val = (val>20.f? val : log1pf(expf(val))) + 1.f;
                size_t chan = ((size_t)(12*cum) + (size_t)((b*3+a_idx)*n + (c-c0)))*S;
                outP[chan + (size_t)y*W + px] = val;
              }
            }
          }
        }
      }
    }
  }
}

// ======== fallback (R13) kernels ========
__global__ __launch_bounds__(256) void k_trans(const float* __restrict__ feat,
    unsigned short* __restrict__ ft, int H, int W, int Wp, int y_begin,
    int slot_base, int RBf)
{
  int t = threadIdx.x;
  int lane = t & 63, wv = t >> 6;
  int x = blockIdx.x*64 + lane;
  int y = y_begin + blockIdx.y;
  int b = blockIdx.z;
  int slot = slot_base + blockIdx.y;
  if (x >= W) return;
  const float* fb = feat + ((size_t)(b*256)*H + y)*W + x;
  unsigned short* dst = ft + (((size_t)b*RBf + slot)*Wp + x + 1)*256;
  #pragma unroll 4
  for (int i=0;i<16;i++){
    int c0 = wv*4 + i*16;
    float v0 = fb[(size_t)(c0+0)*H*W];
    float v1 = fb[(size_t)(c0+1)*H*W];
    float v2 = fb[(size_t)(c0+2)*H*W];
    float v3 = fb[(size_t)(c0+3)*H*W];
    us4 o = { f2bf(v0), f2bf(v1), f2bf(v2), f2bf(v3) };
    *(us4*)(dst + c0) = o;
  }
}

__global__ __launch_bounds__(256) void k_zrow(unsigned short* __restrict__ buf,
    long bStr, int Wp, int slot0, int nslots)
{
  long i = ((long)blockIdx.x*256 + threadIdx.x)*8;
  long per_b = (long)nslots*Wp*256;
  if (i >= 4*per_b) return;
  int b = (int)(i / per_b); long r = i % per_b;
  unsigned short* d = buf + (size_t)b*bStr + (size_t)slot0*Wp*256 + r;
  us4 z = {0,0,0,0};
  *(us4*)d = z; *(us4*)(d+4) = z;
}

__global__ __launch_bounds__(256) void k_zcol(unsigned short* __restrict__ buf,
    int Wp, int RB, int W)
{
  long i = ((long)blockIdx.x*256 + threadIdx.x)*8;
  long tot = (long)4*RB*2*256;
  if (i >= tot) return;
  long u = i/8; int q = (int)(u & 31); int side = (int)((u>>5)&1);
  long bs = u>>6; int slot = (int)(bs % RB); int b = (int)(bs / RB);
  unsigned short* d = buf + (((size_t)b*RB + slot)*Wp + (side? W+1 : 0))*256 + q*8;
  us4 z = {0,0,0,0};
  *(us4*)d = z; *(us4*)(d+4) = z;
}

// ======== weight repacks ========
__global__ __launch_bounds__(256) void k_repack_conv(const float* __restrict__ w,
    const float* __restrict__ g, const float* __restrict__ v,
    unsigned short* __restrict__ wf)
{
  int t = blockIdx.x*256 + threadIdx.x;
  if (t >= 4*256*256) return;
  int ci = t & 255, co = (t>>8) & 255, l = t>>16;
  float s = g[l*256+co] * rsqrtf(v[l*256+co] + EPSV);
  const float* wp = w + (size_t)t*9;
  int cb = co>>4, kc = ci>>5;
  int lane = ((ci>>3)&3)*16 + (co&15);
  int e = ci&7;
  size_t base = (((size_t)(l*16+cb)*8 + kc)*9)*512 + (size_t)lane*8 + e;
  #pragma unroll
  for (int tap=0;tap<9;tap++)
    wf[base + (size_t)tap*512] = f2bf(wp[tap]*s);
}

__global__ __launch_bounds__(256) void k_repack_conv_raw(const float* __restrict__ w,
    unsigned short* __restrict__ wf)
{
  int t = blockIdx.x*256 + threadIdx.x;
  if (t >= 4*256*256) return;
  int ci = t & 255, co = (t>>8) & 255, l = t>>16;
  const float* wp = w + (size_t)t*9;
  int cb = co>>4, kc = ci>>5;
  int lane = ((ci>>3)&3)*16 + (co&15);
  int e = ci&7;
  size_t base = (((size_t)(l*16+cb)*8 + kc)*9)*512 + (size_t)lane*8 + e;
  #pragma unroll
  for (int tap=0;tap<9;tap++)
    wf[base + (size_t)tap*512] = f2bf(wp[tap]);
}

__global__ __launch_bounds__(256) void k_repack_awB(const float* __restrict__ aw,
    unsigned short* __restrict__ out)
{
  int t = blockIdx.x*256 + threadIdx.x;
  if (t >= 4*16*8*64) return;
  int lane = t & 63, kc = (t>>6)&7, cit = (t>>9)&15, l = t>>13;
  int ci = cit*16 + (lane&15);
  int m0 = kc*32 + ((lane>>4))*8;
  unsigned short tmp[8];
  #pragma unroll
  for (int e=0;e<8;e++)
    tmp[e] = f2bf(aw[ ((size_t)(l*256 + m0 + e))*256 + ci ]);
  unsigned short* d = out + (size_t)t*8;
  *(us4*)d = *(us4*)tmp; *(us4*)(d+4) = *(us4*)(tmp+4);
}

__global__ __launch_bounds__(256) void k_fold(
    const unsigned short* __restrict__ w1raw,
    const unsigned short* __restrict__ bawB,
    const float* __restrict__ g, const float* __restrict__ v,
    unsigned short* __restrict__ wf)
{
  int blk = blockIdx.x;              // l*36 + tap*4 + cich
  int cich = blk & 3;
  int tap  = (blk>>2) % 9;
  int l    = blk / 36;
  int tid = threadIdx.x, lane = tid&63, w = tid>>6;
  int l15 = lane&15, g4 = lane>>4;
  f32x4 acc[4][4];
  #pragma unroll
  for (int i=0;i<4;i++)
    #pragma unroll
    for (int j=0;j<4;j++) acc[i][j] = (f32x4){0.f,0.f,0.f,0.f};

  #pragma unroll 1
  for (int kc=0; kc<8; ++kc){
    bf16x8 A[4], B[4];
    #pragma unroll
    for (int cf=0;cf<4;cf++)
      A[cf] = *(const bf16x8*)(w1raw +
        ((((size_t)(l*16 + w*4+cf)*8 + kc)*9 + tap)*512) + (size_t)lane*8);
    #pragma unroll
    for (int pf=0;pf<4;pf++)
      B[pf] = *(const bf16x8*)(bawB +
        (((size_t)(l*16 + cich*4+pf)*8 + kc)*512) + (size_t)lane*8);
    #pragma unroll
    for (int cf=0;cf<4;cf++)
      #pragma unroll
      for (int pf=0;pf<4;pf++)
        acc[cf][pf] = __builtin_amdgcn_mfma_f32_16x16x32_bf16(A[cf], B[pf], acc[cf][pf], 0,0,0);
  }
  #pragma unroll
  for (int cf=0;cf<4;cf++){
    #pragma unroll
    for (int pf=0;pf<4;pf++){
      int ci = cich*64 + pf*16 + l15;
      #pragma unroll
      for (int r=0;r<4;r++){
        int co = w*64 + cf*16 + g4*4 + r;
        float s = g[l*256+co] * rsqrtf(v[l*256+co] + EPSV);
        float val = acc[cf][pf][r] * s;
        int cb = co>>4, kci = ci>>5;
        int dlane = ((ci>>3)&3)*16 + (co&15);
        int e = ci&7;
        wf[ ((((size_t)(l*16+cb)*8 + kci)*9 + tap)*512) + (size_t)dlane*8 + e ] = f2bf(val);
      }
    }
  }
}

__global__ __launch_bounds__(192) void k_repack_pred(const float* __restrict__ w,
    unsigned short* __restrict__ wf)
{
  int t = blockIdx.x*192 + threadIdx.x;
  if (t >= 4*48*32) return;
  int o = t & 31, co = (t>>5)%48, l = t/1536;
  int ci0 = o*8, f = co>>4, kc = o>>2, lane = (o&3)*16 + (co&15);
  unsigned short* dst = wf + ((((size_t)l*8 + kc)*3 + f)*64 + lane)*8;
  #pragma unroll
  for (int e=0;e<8;e++){
    float val = (co<45) ? w[((size_t)(l*45+co)*256 + ci0 + e)] : 0.f;
    dst[e] = f2bf(val);
  }
}

__global__ __launch_bounds__(256) void k_bias(const float* __restrict__ b,
    const float* __restrict__ g, const float* __restrict__ be,
    const float* __restrict__ m, const float* __restrict__ v,
    float* __restrict__ out)
{
  int t = blockIdx.x*256 + threadIdx.x;
  if (t >= 1024) return;
  float s = g[t]*rsqrtf(v[t]+EPSV);
  out[t] = (b[t]-m[t])*s + be[t];
}

__global__ __launch_bounds__(256) void k_bias1f(
    const float* __restrict__ w1, const float* __restrict__ ab,
    const float* __restrict__ b1, const float* __restrict__ g1,
    const float* __restrict__ be1, const float* __restrict__ m1,
    const float* __restrict__ v1, float* __restrict__ bcase)
{
  int t = blockIdx.x*256 + threadIdx.x;
  if (t >= 1024) return;
  int co = t & 255, l = t >> 8;
  float tt[9] = {0,0,0,0,0,0,0,0,0};
  const float* wp  = w1 + ((size_t)(l*256+co)*256)*9;
  const float* abp = ab + l*256;
  for (int m=0;m<256;m++){
    float a = abp[m];
    const float* w9 = wp + (size_t)m*9;
    #pragma unroll
    for (int tap=0;tap<9;tap++) tt[tap] += w9[tap]*a;
  }
  float s = g1[t]*rsqrtf(v1[t]+EPSV);
  float base = be1[t] + s*(b1[t]-m1[t]);
  for (int yc=0;yc<3;yc++)
    for (int xc=0;xc<3;xc++){
      float sum = 0.f;
      #pragma unroll
      for (int tap=0;tap<9;tap++){
        int ky = tap/3, kx = tap%3;
        bool oob = (yc==0&&ky==0)||(yc==2&&ky==2)||(xc==0&&kx==0)||(xc==2&&kx==2);
        if (!oob) sum += tt[tap];
      }
      bcase[ ((size_t)(l*9) + yc*3+xc)*256 + co ] = base + s*sum;
    }
}

// ======== fallback conv kernel (R13's k_conv6) ========
template<int TAPS, bool RELU, bool PRED, bool FOLD>
__global__ __launch_bounds__(256,2) void k_conv6(
    const unsigned short* __restrict__ in, const unsigned short* __restrict__ wf,
    const float* __restrict__ bias, unsigned short* __restrict__ outb,
    int W, int Wp, int y_begin, int y_end, int in_row0, int RBin,
    int out_row0, int RBout,
    const unsigned short* __restrict__ wfP, const float* __restrict__ bp,
    float* __restrict__ outP, int H)
{
  constexpr int ROWS   = 4;
  constexpr int PXS    = 72;
  constexpr int RSTR   = PXS*64;
  constexpr int BUFB   = ROWS*RSTR;
  constexpr int NCHK   = BUFB/1024;
  constexpr int NFULL  = NCHK/4;
  constexpr int NTAIL  = NCHK - NFULL*4;
  constexpr int CPW    = NFULL + 1;
  constexpr int PERROW = PXS*4;
  constexpr int LDSB   = PRED ? 65536 : 2*BUFB;
  __shared__ __align__(1024) char lds[LDSB];

  int tid = threadIdx.x, lane = tid&63, w = tid>>6;
  int l15 = lane&15, g4 = lane>>4;
  int x0 = blockIdx.x*64;
  int y0 = y_begin + 2*blockIdx.y;
  int b  = blockIdx.z;

  size_t rowEl = (size_t)Wp*256;
  const unsigned short* gb =
      in + ((size_t)b*RBin + (y0-1-in_row0))*rowEl + (size_t)x0*256;

  int Poff[CPW], Coff[CPW];
  #pragma unroll
  for (int i=0;i<CPW;i++){
    int c = (i<NFULL) ? (4*i + w) : (4*NFULL + w);
    int s = c*64 + lane;
    int r = s / PERROW;
    int rem = s - r*PERROW;
    int px = rem>>2, sq = rem&3;
    int slot = sq ^ (px&3) ^ ((px>>2)&3);
    Poff[i] = r*(int)rowEl + px*256 + slot*8;
    Coff[i] = c*1024;
  }

  int vb[12];
  #pragma unroll
  for (int kx=0;kx<3;kx++)
    #pragma unroll
    for (int pf=0;pf<4;pf++){
      int px = pf*16 + l15 + kx;
      vb[kx*4+pf] = px*64 + ((g4 ^ (px&3) ^ ((px>>2)&3))<<4);
    }

  const unsigned short* wA = wf + (size_t)(w*4)*(8*TAPS*512) + (size_t)lane*8;

  f32x4 acc0[4][4], acc1[4][4];
  #pragma unroll
  for (int i=0;i<4;i++)
    #pragma unroll
    for (int j=0;j<4;j++){
      acc0[i][j] = (f32x4){0.f,0.f,0.f,0.f};
      acc1[i][j] = (f32x4){0.f,0.f,0.f,0.f};
    }

  const unsigned short* gbk = gb;
  auto stage = [&](int jb){
    #pragma unroll
    for (int i=0;i<NFULL;i++) gload16(gbk + Poff[i], (char*)&lds[0] + jb + Coff[i]);
    if (w < NTAIL) gload16(gbk + Poff[NFULL], (char*)&lds[0] + jb + Coff[NFULL]);
    gbk += 32;
  };

#define LOADB(KY, KX, BV) { \
  _Pragma("unroll") \
  for (int pf=0;pf<4;pf++) BV[pf] = *(const bf16x8*)(base + (KY)*RSTR + vb[(KX)*4+pf]); }

#define LOADA(G, AV) { \
  _Pragma("unroll") \
  for (int cf=0;cf<4;cf++) AV[cf] = *(const bf16x8*)(wk + (size_t)cf*(8*TAPS*512) + (G)*512); }

#define MM(AC, AV, BV) { \
  _Pragma("unroll") for (int cf=0;cf<4;cf++) \
  _Pragma("unroll") for (int pf=0;pf<4;pf++) \
    AC[cf][pf] = __builtin_amdgcn_mfma_f32_16x16x32_bf16(AV[cf], BV[pf], AC[cf][pf], 0,0,0); }

  auto compute = [&](int kc, const char* base){
    const unsigned short* wk = wA + (size_t)kc*(TAPS*512);
    bf16x8 A[4], B0[4], B1[4];
    #pragma unroll
    for (int kx=0;kx<3;kx++){
      LOADB(0,kx,B0) LOADB(1,kx,B1)
      LOADA(0*3+kx,A) MM(acc0,A,B0) MM(acc1,A,B1)
      LOADB(2,kx,B0)
      LOADA(1*3+kx,A) MM(acc0,A,B1) MM(acc1,A,B0)
      LOADB(3,kx,B1)
      LOADA(2*3+kx,A) MM(acc0,A,B0) MM(acc1,A,B1)
    }
  };

  stage(0);
  __syncthreads();
  #pragma unroll 1
  for (int kt=0; kt<4; ++kt){
    stage(BUFB);
    compute(2*kt, (const char*)&lds[0]);
    __syncthreads();
    if (kt < 3) stage(0);
    compute(2*kt+1, (const char*)&lds[0] + BUFB);
    __syncthreads();
  }
#undef LOADB
#undef LOADA
#undef MM

  if constexpr (!PRED){
    bool ok1 = (y0 + 1) < y_end;
    int oslot = y0 - out_row0;
    unsigned short* ob = outb + ((size_t)b*RBout + oslot)*rowEl + 256;
    int yc0 = 1, yc1 = 1;
    if constexpr (FOLD){
      yc0 = (y0==0)?0:((y0==H-1)?2:1);
      yc1 = (y0+1==0)?0:((y0+1==H-1)?2:1);
    }
    #pragma unroll
    for (int cf=0; cf<4; ++cf){
      int co0 = w*64 + cf*16 + g4*4;
      f32x4 bbI = *(const f32x4*)(bias + (FOLD ? 4*256 : 0) + co0);
      #pragma unroll
      for (int pf=0; pf<4; ++pf){
        int x = x0 + pf*16 + l15;
        if (x < W){
          f32x4 b0 = bbI, b1v = bbI;
          if constexpr (FOLD){
            int xc = (x==0)?0:((x==W-1)?2:1);
            b0  = *(const f32x4*)(bias + (yc0*3+xc)*256 + co0);
            b1v = *(const f32x4*)(bias + (yc1*3+xc)*256 + co0);
          }
          float v0 = acc0[cf][pf][0]+b0[0], v1 = acc0[cf][pf][1]+b0[1];
          float v2 = acc0[cf][pf][2]+b0[2], v3 = acc0[cf][pf][3]+b0[3];
          if (RELU){ v0=fmaxf(v0,0.f); v1=fmaxf(v1,0.f); v2=fmaxf(v2,0.f); v3=fmaxf(v3,0.f); }
          us4 o = { f2bf(v0), f2bf(v1), f2bf(v2), f2bf(v3) };
          *(us4*)(ob + (size_t)x*256 + co0) = o;
          if (ok1){
            float u0 = acc1[cf][pf][0]+b1v[0], u1 = acc1[cf][pf][1]+b1v[1];
            float u2 = acc1[cf][pf][2]+b1v[2], u3 = acc1[cf][pf][3]+b1v[3];
            if (RELU){ u0=fmaxf(u0,0.f); u1=fmaxf(u1,0.f); u2=fmaxf(u2,0.f); u3=fmaxf(u3,0.f); }
            us4 o1 = { f2bf(u0), f2bf(u1), f2bf(u2), f2bf(u3) };
            *(us4*)(ob + rowEl + (size_t)x*256 + co0) = o1;
          }
        }
      }
    }
  } else {
    __syncthreads();
    unsigned short* xs = (unsigned short*)&lds[0];
    #pragma unroll
    for (int cf=0; cf<4; ++cf){
      int co0 = w*64 + cf*16 + g4*4;
      f32x4 bb = *(const f32x4*)(bias + co0);
      int c16 = co0 >> 3;
      int sub = (g4 & 1) * 8;
      #pragma unroll
      for (int pf=0; pf<4; ++pf){
        int px = pf*16 + l15;
        int slot = c16 ^ (px & 31);
        float v0 = fmaxf(acc0[cf][pf][0]+bb[0],0.f), v1 = fmaxf(acc0[cf][pf][1]+bb[1],0.f);
        float v2 = fmaxf(acc0[cf][pf][2]+bb[2],0.f), v3 = fmaxf(acc0[cf][pf][3]+bb[3],0.f);
        us4 o0 = { f2bf(v0), f2bf(v1), f2bf(v2), f2bf(v3) };
        *(us4*)((char*)xs + ((px*32 + slot)<<4) + sub) = o0;
        float u0 = fmaxf(acc1[cf][pf][0]+bb[0],0.f), u1 = fmaxf(acc1[cf][pf][1]+bb[1],0.f);
        float u2 = fmaxf(acc1[cf][pf][2]+bb[2],0.f), u3 = fmaxf(acc1[cf][pf][3]+bb[3],0.f);
        us4 o1 = { f2bf(u0), f2bf(u1), f2bf(u2), f2bf(u3) };
        *(us4*)((char*)xs + 32768 + ((px*32 + slot)<<4) + sub) = o1;
      }
    }
    __syncthreads();

    int rw2 = w & 1, pxg = w >> 1;
    f32x4 ap[3][2];
    #pragma unroll
    for (int f=0;f<3;f++){ ap[f][0] = (f32x4){0,0,0,0}; ap[f][1] = (f32x4){0,0,0,0}; }
    #pragma unroll
    for (int kc=0;kc<8;kc++){
      bf16x8 Bf[2];
      #pragma unroll
      for (int t2=0;t2<2;t2++){
        int px = (pxg*2+t2)*16 + l15;
        int slot = (kc*4 + g4) ^ (px & 31);
        Bf[t2] = *(const bf16x8*)((char*)xs + rw2*32768 + ((px*32 + slot)<<4));
      }
      #pragma unroll
      for (int f=0;f<3;f++){
        bf16x8 Af = *(const bf16x8*)(wfP + (((size_t)kc*3 + f)*64 + lane)*8);
        ap[f][0] = __builtin_amdgcn_mfma_f32_16x16x32_bf16(Af, Bf[0], ap[f][0], 0,0,0);
        ap[f][1] = __builtin_amdgcn_mfma_f32_16x16x32_bf16(Af, Bf[1], ap[f][1], 0,0,0);
      }
    }
    int y = y0 + rw2;
    if (y < y_end){
      size_t S = (size_t)H*W;
      #pragma unroll
      for (int f=0;f<3;f++){
        #pragma unroll
        for (int t2=0;t2<2;t2++){
          int px = x0 + (pxg*2+t2)*16 + l15;
          if (px < W){
            #pragma unroll
            for (int r=0;r<4;r++){
              int co = f*16 + g4*4 + r;
              if (co < 45){
                float val = ap[f][t2][r] + bp[co];
                int a_idx = co/15, c = co%15;
                int cum,c0,n;
                if (c<4)       {cum=0;c0=0;n=4;}
                else if (c==4) {cum=4;c0=4;n=1;}
                else if (c<10) {cum=5;c0=5;n=5;}
                else if (c<14) {cum=10;c0=10;n=4;}
                else           {cum=14;c0=14;n=1;}
                if (c==4) val = 1.f/(1.f+expf(-val));
                else if (c==14) val = (val>20.f? val : log1pf(expf(val))) + 1.f;
                size_t chan = ((size_t)(12*cum) + (size_t)((b*3+a_idx)*n + (c-c0)))*S;
                outP[chan + (size_t)y*W + px] = val;
              }
            }
          }
        }
      }
    }
  }
}

// ======== host ========
extern "C" void kernel_launch(void* const* d_in, const int* in_sizes, int n_in,
                              void* d_out, int out_size, void* d_ws, size_t ws_size,
                              hipStream_t stream)
{
  static const int Hs[4] = {192,96,48,24};
  static const int Wd[4] = {320,160,80,40};
  const float* feat[4] = {(const float*)d_in[0],(const float*)d_in[1],
                          (const float*)d_in[2],(const float*)d_in[3]};
  const float* adapt_w = (const float*)d_in[4];
  const float* adapt_b = (const float*)d_in[5];
  const float* w1 = (const float*)d_in[6];  const float* b1 = (const float*)d_in[7];
  const float* g1 = (const float*)d_in[8];  const float* be1= (const float*)d_in[9];
  const float* m1 = (const float*)d_in[10]; const float* v1 = (const float*)d_in[11];
  const float* w2 = (const float*)d_in[12]; const float* b2 = (const float*)d_in[13];
  const float* g2 = (const float*)d_in[14]; const float* be2= (const float*)d_in[15];
  const float* m2 = (const float*)d_in[16]; const float* v2 = (const float*)d_in[17];
  const float* wp = (const float*)d_in[18]; const float* bp = (const float*)d_in[19];
  float* out = (float*)d_out;

  char* base = (char*)d_ws;
  size_t off = 0;
  auto alloc = [&](size_t bytes)->char*{
    char* p = base + off; off = (off + bytes + 255) & ~(size_t)255; return p; };

  const size_t WF3_L = (size_t)16*8*9*512;
  const size_t WAB_L = (size_t)16*8*512;
  const size_t WFP_L = (size_t)8*3*512;
  unsigned short* wf1raw = (unsigned short*)alloc(4*WF3_L*2);
  unsigned short* bawB   = (unsigned short*)alloc(4*WAB_L*2);
  unsigned short* wf1f   = (unsigned short*)alloc(4*WF3_L*2);
  unsigned short* wf2    = (unsigned short*)alloc(4*WF3_L*2);
  unsigned short* wfP    = (unsigned short*)alloc(4*WFP_L*2);
  float* bcase1 = (float*)alloc(4*9*256*4);
  float* biasc2 = (float*)alloc(1024*4);
  char*  bufbase = base + off;
  size_t rem = (ws_size > off + 65536) ? (ws_size - off - 65536) : 0;

  k_repack_conv_raw<<<dim3(1024), dim3(256), 0, stream>>>(w1, wf1raw);
  k_repack_awB     <<<dim3(128),  dim3(256), 0, stream>>>(adapt_w, bawB);
  k_repack_conv    <<<dim3(1024), dim3(256), 0, stream>>>(w2, g2, v2, wf2);
  k_repack_pred    <<<dim3(32),   dim3(192), 0, stream>>>(wp, wfP);
  k_bias1f<<<dim3(4), dim3(256), 0, stream>>>(w1, adapt_b, b1, g1, be1, m1, v1, bcase1);
  k_bias  <<<dim3(4), dim3(256), 0, stream>>>(b2, g2, be2, m2, v2, biasc2);
  k_fold  <<<dim3(144), dim3(256), 0, stream>>>(wf1raw, bawB, g1, v1, wf1f);

  // ---- try fused (all-levels-resident) path ----
  size_t ftOff[4], b1Off[4], cur = 0;
  for (int l=0;l<4;l++){
    int H = Hs[l], Wp = Wd[l]+2;
    size_t rowEl = (size_t)Wp*256;
    ftOff[l] = cur; cur += (size_t)4*(H+4)*rowEl;
    b1Off[l] = cur; cur += (size_t)4*(H+2)*rowEl;
  }
  bool fused = (rem >= cur*2);

  if (fused){
    unsigned short* wsbuf = (unsigned short*)bufbase;

    // zero-border job table
    ZTab Z; unsigned long long zc = 0;
    int j = 0;
    for (int l=0;l<4;l++){
      int H = Hs[l], W = Wd[l], Wp = W+2;
      size_t rowEl = (size_t)Wp*256;
      int RBf = H+4, RB1 = H+2;
      // featT top 2 rows, bottom 2 rows
      Z.off[j]=ftOff[l];                    Z.rowLen[j]=(int)(2*rowEl); Z.rowStride[j]=(int)((size_t)RBf*rowEl); Z.cum[j]=zc; zc += (unsigned long long)4*(2*rowEl/8); j++;
      Z.off[j]=ftOff[l]+(size_t)(H+2)*rowEl;Z.rowLen[j]=(int)(2*rowEl); Z.rowStride[j]=(int)((size_t)RBf*rowEl); Z.cum[j]=zc; zc += (unsigned long long)4*(2*rowEl/8); j++;
      // featT left/right cols
      Z.off[j]=ftOff[l];                    Z.rowLen[j]=256; Z.rowStride[j]=(int)rowEl; Z.cum[j]=zc; zc += (unsigned long long)4*RBf*32; j++;
      Z.off[j]=ftOff[l]+(size_t)(W+1)*256;  Z.rowLen[j]=256; Z.rowStride[j]=(int)rowEl; Z.cum[j]=zc; zc += (unsigned long long)4*RBf*32; j++;
      // buf1 top 1 row, bottom 1 row
      Z.off[j]=b1Off[l];                    Z.rowLen[j]=(int)rowEl; Z.rowStride[j]=(int)((size_t)RB1*rowEl); Z.cum[j]=zc; zc += (unsigned long long)4*(rowEl/8); j++;
      Z.off[j]=b1Off[l]+(size_t)(H+1)*rowEl;Z.rowLen[j]=(int)rowEl; Z.rowStride[j]=(int)((size_t)RB1*rowEl); Z.cum[j]=zc; zc += (unsigned long long)4*(rowEl/8); j++;
      // buf1 left/right cols
      Z.off[j]=b1Off[l];                    Z.rowLen[j]=256; Z.rowStride[j]=(int)rowEl; Z.cum[j]=zc; zc += (unsigned long long)4*RB1*32; j++;
      Z.off[j]=b1Off[l]+(size_t)(W+1)*256;  Z.rowLen[j]=256; Z.rowStride[j]=(int)rowEl; Z.cum[j]=zc; zc += (unsigned long long)4*RB1*32; j++;
    }
    Z.cum[NZJOB] = zc;
    unsigned zgrid = (unsigned)((zc + 255) / 256);
    k_zeroB<<<dim3(zgrid), dim3(256), 0, stream>>>(wsbuf, Z);

    // fused trans
    TrP T; T.cum[0] = 0;
    for (int l=0;l<4;l++){
      T.W[l]=Wd[l]; T.Wp[l]=Wd[l]+2; T.H[l]=Hs[l];
      T.nPx[l]=(Wd[l]+63)/64; T.ftOff[l]=ftOff[l];
      T.cum[l+1] = T.cum[l] + T.nPx[l]*Hs[l]*4;
    }
    k_transF<<<dim3((unsigned)T.cum[4]), dim3(256), 0, stream>>>(
        feat[0], feat[1], feat[2], feat[3], wsbuf, T);

    // fused conv1' and conv2P
    CvP C1, C2; C1.cum[0]=0; C2.cum[0]=0;
    size_t out_off = 0;
    for (int l=0;l<4;l++){
      int H=Hs[l], W=Wd[l];
      C1.W[l]=C2.W[l]=W; C1.Wp[l]=C2.Wp[l]=W+2; C1.H[l]=C2.H[l]=H;
      C1.nPx[l]=C2.nPx[l]=(W+63)/64;
      int nR=(H+1)/2;
      C1.nRows[l]=C2.nRows[l]=nR;
      C1.inOff[l]=ftOff[l];  C1.outOff[l]=b1Off[l]; C1.outPOff[l]=0;
      C2.inOff[l]=b1Off[l];  C2.outOff[l]=0;        C2.outPOff[l]=out_off;
      int cnt = C1.nPx[l]*nR*4;
      C1.cum[l+1]=C1.cum[l]+cnt; C2.cum[l+1]=C2.cum[l]+cnt;
      out_off += (size_t)4*45*H*W;
    }
    k_convF<false><<<dim3((unsigned)C1.cum[4]), dim3(256), 0, stream>>>(
        wsbuf, C1, wf1f, bcase1, wfP, bp, out);
    k_convF<true><<<dim3((unsigned)C2.cum[4]), dim3(256), 0, stream>>>(
        wsbuf, C2, wf2, biasc2, wfP, bp, out);
    return;
  }

  // ---- fallback: R13 per-level chunked path ----
  size_t out_off = 0;
  for (int l=0;l<4;l++){
    int H = Hs[l], W = Wd[l], Wp = W + 2;
    size_t S = (size_t)H*W;
    size_t rowEl = (size_t)Wp*256;
    long slotsAvail = (long)(rem / (rowEl*2));
    long Rl = (slotsAvail - 60) / 8;
    int R = (int)(Rl < 2 ? 2 : (Rl > H ? (long)H : Rl));
    int RBf = R + 4, RB1 = R + 2;
    unsigned short* featT = (unsigned short*)bufbase;
    unsigned short* buf1  = featT + ((size_t)4*RBf + 8)*rowEl;
    int nPxT = (W + 63) / 64;
    long zcGrid0 = ((long)4*RBf*2*256 + 2047)/2048;
    long zcGrid1 = ((long)4*RB1*2*256 + 2047)/2048;
    k_zcol<<<dim3((unsigned)zcGrid0), dim3(256), 0, stream>>>(featT, Wp, RBf, W);
    k_zcol<<<dim3((unsigned)zcGrid1), dim3(256), 0, stream>>>(buf1, Wp, RB1, W);

    for (int r0 = 0; r0 < H; r0 += R){
      int r1 = (r0 + R < H) ? (r0 + R) : H;
      int Rc = r1 - r0;
      int ya0 = (r0-2 < 0) ? 0 : r0-2;
      int ya1 = (r1+2 > H) ? H : r1+2;
      int yb0 = (r0-1 < 0) ? 0 : r0-1;
      int yb1 = (r1+1 > H) ? H : r1+1;

      if (r0 == 0){
        long zg = ((long)4*2*Wp*256 + 2047)/2048;
        k_zrow<<<dim3((unsigned)zg), dim3(256), 0, stream>>>(featT, (long)RBf*Wp*256, Wp, 0, 2);
        long zg1 = ((long)4*1*Wp*256 + 2047)/2048;
        k_zrow<<<dim3((unsigned)zg1), dim3(256), 0, stream>>>(buf1, (long)RB1*Wp*256, Wp, 0, 1);
      }
      if (r1 == H){
        long zg = ((long)4*2*Wp*256 + 2047)/2048;
        k_zrow<<<dim3((unsigned)zg), dim3(256), 0, stream>>>(featT, (long)RBf*Wp*256, Wp, Rc+2, 2);
        long zg1 = ((long)4*1*Wp*256 + 2047)/2048;
        k_zrow<<<dim3((unsigned)zg1), dim3(256), 0, stream>>>(buf1, (long)RB1*Wp*256, Wp, Rc+1, 1);
      }

      k_trans<<<dim3(nPxT, ya1-ya0, 4), dim3(256), 0, stream>>>(
          feat[l], featT, H, W, Wp, ya0, ya0-(r0-2), RBf);

      k_conv6<9,true,false,true><<<dim3(nPxT, (yb1-yb0+1)/2, 4), dim3(256), 0, stream>>>(
          featT, wf1f + (size_t)l*WF3_L, bcase1 + (size_t)l*9*256, buf1,
          W, Wp, yb0, yb1, r0-2, RBf, r0-1, RB1,
          nullptr, nullptr, nullptr, H);

      k_conv6<9,true,true,false><<<dim3(nPxT, (Rc+1)/2, 4), dim3(256), 0, stream>>>(
          buf1, wf2 + (size_t)l*WF3_L, biasc2 + l*256, nullptr,
          W, Wp, r0, r1, r0-1, RB1, 0, 0,
          wfP + (size_t)l*WFP_L, bp + l*45, out + out_off, H);
    }
    out_off += (size_t)4*45*S;
  }
}